// Round 10
// baseline (19408.084 us; speedup 1.0000x reference)
//
#include <hip/hip_runtime.h>

#define R     8192
#define C1    8213
#define C2    8192
#define KROW  8224      // K row stride in BYTES (514 x 16B chunks, zero-padded)
#define TROW  8192      // KT row stride in BYTES (512 x 16B chunks)
#define NKC   514
#define NTC   512
#define NBLK  1024      // persistent grid (4 blocks/CU by capacity)
#define TPB   512
#define CPF   8224      // v length in floats

// LDS staging slot (16B units): chunk c's float4 #r at (c&63) + r*64 + (c>>6)*256
#define SLOT0(c) (((c) & 63) + (((c) >> 6) << 8))

typedef float f32x2 __attribute__((ext_vector_type(2)));

__device__ __forceinline__ void fp8x16_to_f(const int4 w, float f[16]) {
    f32x2 p;
    p = __builtin_amdgcn_cvt_pk_f32_fp8(w.x, false); f[0]  = p.x; f[1]  = p.y;
    p = __builtin_amdgcn_cvt_pk_f32_fp8(w.x, true);  f[2]  = p.x; f[3]  = p.y;
    p = __builtin_amdgcn_cvt_pk_f32_fp8(w.y, false); f[4]  = p.x; f[5]  = p.y;
    p = __builtin_amdgcn_cvt_pk_f32_fp8(w.y, true);  f[6]  = p.x; f[7]  = p.y;
    p = __builtin_amdgcn_cvt_pk_f32_fp8(w.z, false); f[8]  = p.x; f[9]  = p.y;
    p = __builtin_amdgcn_cvt_pk_f32_fp8(w.z, true);  f[10] = p.x; f[11] = p.y;
    p = __builtin_amdgcn_cvt_pk_f32_fp8(w.w, false); f[12] = p.x; f[13] = p.y;
    p = __builtin_amdgcn_cvt_pk_f32_fp8(w.w, true);  f[14] = p.x; f[15] = p.y;
}

__device__ __forceinline__ float fp8_to_f(int byte) {
    f32x2 p = __builtin_amdgcn_cvt_pk_f32_fp8(byte & 0xff, false);
    return p.x;
}

__device__ __forceinline__ float gm_label(float sc, int lab) {
    if (lab == 0) return fmaxf(-0.02f - sc, 0.0f) + fmaxf(sc, 0.0f);
    if (lab == 3) return fmaxf(0.09f + sc, 0.0f);
    return fmaxf(0.05f + sc, 0.0f) + fmaxf(-0.09f - sc, 0.0f); // labels 1|2
}

__device__ __forceinline__ float kval(float gm) {
    // K = exp(-M/REG), M = exp(-GM), REG = -0.2 -> exp(5*exp(-GM)); hw exp
    return __expf(5.0f * __expf(-gm));
}

__device__ __forceinline__ float sum16(const float f[16]) {
    float d = 0.0f;
#pragma unroll
    for (int k = 0; k < 16; ++k) d += f[k];
    return d;
}

__device__ __forceinline__ float dotw(const float f[16], float4 w0, float4 w1,
                                      float4 w2, float4 w3, float p) {
    p = fmaf(f[0], w0.x, p);  p = fmaf(f[1], w0.y, p);
    p = fmaf(f[2], w0.z, p);  p = fmaf(f[3], w0.w, p);
    p = fmaf(f[4], w1.x, p);  p = fmaf(f[5], w1.y, p);
    p = fmaf(f[6], w1.z, p);  p = fmaf(f[7], w1.w, p);
    p = fmaf(f[8], w2.x, p);  p = fmaf(f[9], w2.y, p);
    p = fmaf(f[10], w2.z, p); p = fmaf(f[11], w2.w, p);
    p = fmaf(f[12], w3.x, p); p = fmaf(f[13], w3.y, p);
    p = fmaf(f[14], w3.z, p); p = fmaf(f[15], w3.w, p);
    return p;
}

// ---- build kernels (R5-proven) ----

__global__ __launch_bounds__(256) void build_k1(const float* __restrict__ dist,
                                                const int* __restrict__ lab,
                                                unsigned char* __restrict__ K) {
    int row = blockIdx.y;
    int j0 = (blockIdx.x * 256 + threadIdx.x) * 4;
    if (j0 >= KROW) return;
    size_t ib = (size_t)row * C1;
    float d0 = dist[ib];
    float val[4];
#pragma unroll
    for (int k = 0; k < 4; ++k) {
        int j = j0 + k;
        val[k] = 0.0f;
        if (j < C1) {
            float g = gm_label(dist[ib + j] - d0, lab[ib + j]);
            val[k] = kval(g);
        }
    }
    int p = 0;
    p = __builtin_amdgcn_cvt_pk_fp8_f32(val[0], val[1], p, false);
    p = __builtin_amdgcn_cvt_pk_fp8_f32(val[2], val[3], p, true);
    *reinterpret_cast<int*>(K + (size_t)row * KROW + j0) = p;
}

__global__ __launch_bounds__(256) void diag_k(const float* __restrict__ dist,
                                              float* __restrict__ dcol) {
    int j = blockIdx.x * 256 + threadIdx.x;
    if (j < R) dcol[j] = dist[(size_t)j * C1 + 21 + j];
}

__global__ __launch_bounds__(256) void build_k2(const float* __restrict__ dist,
                                                const float* __restrict__ dcol,
                                                unsigned char* __restrict__ K) {
    int row = blockIdx.y;
    int j0 = (blockIdx.x * 256 + threadIdx.x) * 4;
    if (j0 >= KROW) return;
    size_t ib = (size_t)row * C1 + 21;
    float val[4];
#pragma unroll
    for (int k = 0; k < 4; ++k) {
        int j = j0 + k;
        val[k] = 0.0f;
        if (j < C2) {
            float s = dist[ib + j] - dcol[j];
            float g = (j == row) ? 0.0f : fmaxf(0.09f + s, 0.0f);
            val[k] = kval(g);
        }
    }
    int p = 0;
    p = __builtin_amdgcn_cvt_pk_fp8_f32(val[0], val[1], p, false);
    p = __builtin_amdgcn_cvt_pk_fp8_f32(val[2], val[3], p, true);
    *reinterpret_cast<int*>(K + (size_t)row * KROW + j0) = p;
}

// ---- byte transpose K[8192][KROW] -> KT[8224][TROW] via 64x64 LDS tile ----
__global__ __launch_bounds__(256) void transpose_k(const unsigned char* __restrict__ K,
                                                   unsigned char* __restrict__ KT) {
    __shared__ unsigned char tile[64][64];
    int i0 = blockIdx.x * 64;
    int j0 = blockIdx.y * 64;
    int t = threadIdx.x;
    int r = t >> 2, cb = (t & 3) << 4;
    if (j0 + cb < KROW) {
        int4 w = *reinterpret_cast<const int4*>(K + (size_t)(i0 + r) * KROW + j0 + cb);
        *reinterpret_cast<int4*>(&tile[r][cb]) = w;
    }
    __syncthreads();
    int jl = t >> 2, ib = (t & 3) << 4;
    if (j0 + jl < KROW) {
        unsigned char tmp[16];
#pragma unroll
        for (int k = 0; k < 16; ++k) tmp[k] = tile[ib + k][jl];
        *reinterpret_cast<int4*>(KT + (size_t)(j0 + jl) * TROW + i0 + ib) =
            *reinterpret_cast<const int4*>(tmp);
    }
}

// ---- barrier: 64 arrival lines, wave-parallel aggregate, 64 epoch lines;
//      RELAXED polls + one acquire fence on exit ----

__global__ void zero_bar(unsigned* __restrict__ bar) {
    int i = threadIdx.x;
    if (i < 128) bar[i << 6] = 0u;
}

__device__ __forceinline__ void gridbar(unsigned* __restrict__ ctr,
                                        unsigned* __restrict__ ep,
                                        int b, unsigned k) {
    __syncthreads();
    if (threadIdx.x == 0)
        __hip_atomic_fetch_add(&ctr[(b & 63) << 6], 1u, __ATOMIC_RELEASE,
                               __HIP_MEMORY_SCOPE_AGENT);
    if (b == 0) {
        if (threadIdx.x < 64) {
            int l = threadIdx.x;
            const unsigned target = k * (unsigned)NBLK;
            for (;;) {
                unsigned s = __hip_atomic_load(&ctr[l << 6], __ATOMIC_RELAXED,
                                               __HIP_MEMORY_SCOPE_AGENT);
#pragma unroll
                for (int off = 32; off; off >>= 1) s += __shfl_down(s, off, 64);
                s = __shfl(s, 0, 64);
                if (s >= target) break;
                __builtin_amdgcn_s_sleep(1);
            }
            __builtin_amdgcn_fence(__ATOMIC_ACQUIRE, "agent");
            __hip_atomic_store(&ep[l << 6], k, __ATOMIC_RELEASE,
                               __HIP_MEMORY_SCOPE_AGENT);
        }
    } else {
        if (threadIdx.x == 0) {
            unsigned* my = &ep[(b & 63) << 6];
            while (__hip_atomic_load(my, __ATOMIC_RELAXED,
                                     __HIP_MEMORY_SCOPE_AGENT) < k)
                __builtin_amdgcn_s_sleep(2);
            __builtin_amdgcn_fence(__ATOMIC_ACQUIRE, "agent");
        }
    }
    __syncthreads();
}

// ---- persistent Sinkhorn: 1024 blocks x 512 thr, 1 row per wave per phase;
//      u/v staged in LDS (swizzled, conflict-free b128 reads); R8 access pattern ----
__global__ __launch_bounds__(TPB, 8) void sink_k(const unsigned char* __restrict__ K,
                                                 const unsigned char* __restrict__ KT,
                                                 float* __restrict__ u,
                                                 float* __restrict__ v,
                                                 unsigned* __restrict__ ctr,
                                                 unsigned* __restrict__ ep,
                                                 int C, float aval, float bval) {
    __shared__ float4 st[2304];
    const int tx = threadIdx.x, b = blockIdx.x;
    const int lane = tx & 63, wv = tx >> 6;
    const int4* Kb = reinterpret_cast<const int4*>(K);
    const int4* KTb = reinterpret_cast<const int4*>(KT);
    const float4* u4 = reinterpret_cast<const float4*>(u);
    const float4* v4 = reinterpret_cast<const float4*>(v);
    const bool spec = (b & 31) == 0;
    const int je = 8192 + (b >> 5);
    const int rbase = b * 8;
    unsigned bark = 0;

    for (int t = 0; t < 50; ++t) {
        // ---- column phase: v[j] = bval / (KT[j] . u) ----
        if (t > 0) {
            // stage u: 512 chunks, thread tx stages chunk tx
            const float4* g = u4 + tx * 4;
            int s0 = SLOT0(tx);
            st[s0]       = g[0];
            st[s0 + 64]  = g[1];
            st[s0 + 128] = g[2];
            st[s0 + 192] = g[3];
            __syncthreads();
        }
        {
            int ja = rbase + wv;
            const int4* Ka = KTb + (size_t)ja * NTC;
            float p = 0.0f;
            if (t == 0) {
#pragma unroll
                for (int s = 0; s < 8; ++s) {
                    float f[16];
                    fp8x16_to_f(Ka[s * 64 + lane], f);
                    p += sum16(f);
                }
                p *= aval;
            } else {
#pragma unroll
                for (int s = 0; s < 8; ++s) {
                    int sb = lane + s * 256;
                    float4 w0 = st[sb], w1 = st[sb + 64], w2 = st[sb + 128], w3 = st[sb + 192];
                    float f[16];
                    fp8x16_to_f(Ka[s * 64 + lane], f);
                    p = dotw(f, w0, w1, w2, w3, p);
                }
            }
#pragma unroll
            for (int off = 32; off; off >>= 1) p += __shfl_xor(p, off, 64);
            if (lane == 0) v[ja] = (ja < C) ? bval / p : 0.0f;
            if (spec && wv == 0) {
                const int4* Ke = KTb + (size_t)je * NTC;
                float q = 0.0f;
                if (t == 0) {
#pragma unroll
                    for (int s = 0; s < 8; ++s) {
                        float f[16];
                        fp8x16_to_f(Ke[s * 64 + lane], f);
                        q += sum16(f);
                    }
                    q *= aval;
                } else {
#pragma unroll
                    for (int s = 0; s < 8; ++s) {
                        int sb = lane + s * 256;
                        float4 w0 = st[sb], w1 = st[sb + 64], w2 = st[sb + 128], w3 = st[sb + 192];
                        float f[16];
                        fp8x16_to_f(Ke[s * 64 + lane], f);
                        q = dotw(f, w0, w1, w2, w3, q);
                    }
                }
#pragma unroll
                for (int off = 32; off; off >>= 1) q += __shfl_xor(q, off, 64);
                if (lane == 0) v[je] = (je < C) ? bval / q : 0.0f;
            }
        }
        if (t == 49) break;
        gridbar(ctr, ep, b, ++bark);

        // ---- row phase: u[i] = aval / (K[i] . v) ----
        {
            // stage v: 514 chunks
            {
                const float4* g = v4 + tx * 4;
                int s0 = SLOT0(tx);
                st[s0]       = g[0];
                st[s0 + 64]  = g[1];
                st[s0 + 128] = g[2];
                st[s0 + 192] = g[3];
                if (tx < 2) {
                    int c = 512 + tx;
                    const float4* gt = v4 + c * 4;
                    int st0 = SLOT0(c);
                    st[st0]       = gt[0];
                    st[st0 + 64]  = gt[1];
                    st[st0 + 128] = gt[2];
                    st[st0 + 192] = gt[3];
                }
            }
            __syncthreads();
            int ra = rbase + wv;
            const int4* Ka = Kb + (size_t)ra * NKC;
            float p = 0.0f;
#pragma unroll
            for (int s = 0; s < 8; ++s) {
                int sb = lane + s * 256;
                float4 w0 = st[sb], w1 = st[sb + 64], w2 = st[sb + 128], w3 = st[sb + 192];
                float f[16];
                fp8x16_to_f(Ka[s * 64 + lane], f);
                p = dotw(f, w0, w1, w2, w3, p);
            }
            if (lane < 2) {
                int c = 512 + lane;
                int sb = (c & 63) + 2048;
                float4 w0 = st[sb], w1 = st[sb + 64], w2 = st[sb + 128], w3 = st[sb + 192];
                float f[16];
                fp8x16_to_f(Ka[c], f);
                p = dotw(f, w0, w1, w2, w3, p);
            }
#pragma unroll
            for (int off = 32; off; off >>= 1) p += __shfl_xor(p, off, 64);
            if (lane == 0) u[ra] = aval / p;
        }
        gridbar(ctr, ep, b, ++bark);
    }
}

// ---- loss reductions (R5-proven) ----

__device__ __forceinline__ float2 block_reduce_2(float x, float y, float* sb) {
#pragma unroll
    for (int off = 32; off; off >>= 1) {
        x += __shfl_down(x, off, 64);
        y += __shfl_down(y, off, 64);
    }
    if ((threadIdx.x & 63) == 0) {
        int w = threadIdx.x >> 6;
        sb[w] = x; sb[4 + w] = y;
    }
    __syncthreads();
    float2 r;
    r.x = sb[0] + sb[1] + sb[2] + sb[3];
    r.y = sb[4] + sb[5] + sb[6] + sb[7];
    __syncthreads();
    return r;
}

__global__ __launch_bounds__(256) void loss1_k(const unsigned char* __restrict__ K,
                                               const float* __restrict__ v,
                                               const float* __restrict__ dist,
                                               const int* __restrict__ lab,
                                               float* __restrict__ ratio) {
    __shared__ float sb[8];
    int i = blockIdx.x;
    size_t ib = (size_t)i * C1;
    float d0 = dist[ib];
    const unsigned char* Kr = K + (size_t)i * KROW;
    float num = 0, den = 0;
    for (int j0 = threadIdx.x * 4; j0 < C1; j0 += 1024) {
        int p = *reinterpret_cast<const int*>(Kr + j0);
#pragma unroll
        for (int k = 0; k < 4; ++k) {
            int j = j0 + k;
            int jc = (j < C1) ? j : (C1 - 1);
            float kv = fp8_to_f(p >> (k * 8)) * v[jc];   // K pad = 0 -> kv = 0 beyond C1
            float g = gm_label(dist[ib + jc] - d0, lab[ib + jc]);
            den += kv;
            num = fmaf(g, kv, num);
        }
    }
    float2 r = block_reduce_2(num, den, sb);
    if (threadIdx.x == 0) ratio[i] = r.x / r.y;
}

__global__ __launch_bounds__(256) void loss2_k(const unsigned char* __restrict__ K,
                                               const float* __restrict__ v,
                                               const float* __restrict__ dist,
                                               const float* __restrict__ dcol,
                                               float* __restrict__ ratio) {
    __shared__ float sb[8];
    int i = blockIdx.x;
    const unsigned char* Kr = K + (size_t)i * KROW;
    const float* Dr = dist + (size_t)i * C1 + 21;
    float num = 0, den = 0;
    for (int j0 = threadIdx.x * 4; j0 < C2; j0 += 1024) {
        int p = *reinterpret_cast<const int*>(Kr + j0);
#pragma unroll
        for (int k = 0; k < 4; ++k) {
            int j = j0 + k;
            if (j == i) continue;
            float kv = fp8_to_f(p >> (k * 8)) * v[j];
            float h = fmaxf(0.09f + Dr[j] - dcol[j], 0.0f);
            den += kv;
            num = fmaf(h, kv, num);
        }
    }
    float2 r = block_reduce_2(num, den, sb);
    if (threadIdx.x == 0) ratio[i] = r.x / r.y;
}

__global__ __launch_bounds__(256) void final_k(const float* __restrict__ r1,
                                               const float* __restrict__ r2,
                                               float* __restrict__ out) {
    __shared__ float sb[8];
    float s1 = 0, s2 = 0;
    for (int i = threadIdx.x; i < R; i += 256) { s1 += r1[i]; s2 += r2[i]; }
    float2 t = block_reduce_2(s1, s2, sb);
    if (threadIdx.x == 0)
        out[0] = t.x / ((float)R * (float)C1) + t.y / ((float)R * (float)C2);
}

extern "C" void kernel_launch(void* const* d_in, const int* in_sizes, int n_in,
                              void* d_out, int out_size, void* d_ws, size_t ws_size,
                              hipStream_t stream) {
    const float* dist = (const float*)d_in[0];
    const int* lab = (const int*)d_in[1];
    float* out = (float*)d_out;
    char* ws = (char*)d_ws;

    size_t need = (size_t)R * KROW                       // K (fp8)
                + (size_t)KROW * TROW                    // KT (fp8)
                + (size_t)CPF * sizeof(float)            // v
                + 4 * (size_t)R * sizeof(float)          // u, dcol, rat1, rat2
                + 128 * 256;                             // barrier lines
    if (ws_size < need) return;

    size_t off = 0;
    unsigned char* K = (unsigned char*)(ws + off);  off += (size_t)R * KROW;
    unsigned char* KT = (unsigned char*)(ws + off); off += (size_t)KROW * TROW;
    float* v = (float*)(ws + off);     off += (size_t)CPF * sizeof(float);
    float* u = (float*)(ws + off);     off += (size_t)R * sizeof(float);
    float* dcol = (float*)(ws + off);  off += (size_t)R * sizeof(float);
    float* rat1 = (float*)(ws + off);  off += (size_t)R * sizeof(float);
    float* rat2 = (float*)(ws + off);  off += (size_t)R * sizeof(float);
    unsigned* bar = (unsigned*)(ws + off); off += 128 * 256;
    unsigned* ctr = bar;              // 64 lines
    unsigned* epb = bar + 64 * 64;    // 64 lines

    float aval = 1.0f / (float)R;
    int gb = (KROW / 4 + 255) / 256;   // 9 blocks per row

    // ---- phase 1 ----
    build_k1<<<dim3(gb, R), 256, 0, stream>>>(dist, lab, K);
    transpose_k<<<dim3(R / 64, (KROW + 63) / 64), 256, 0, stream>>>(K, KT);
    zero_bar<<<dim3(1), 128, 0, stream>>>(bar);
    sink_k<<<dim3(NBLK), TPB, 0, stream>>>(K, KT, u, v, ctr, epb, C1, aval,
                                           1.0f / (float)C1);
    loss1_k<<<dim3(R), 256, 0, stream>>>(K, v, dist, lab, rat1);

    // ---- phase 2 (reuses K and KT buffers) ----
    diag_k<<<dim3(R / 256), 256, 0, stream>>>(dist, dcol);
    build_k2<<<dim3(gb, R), 256, 0, stream>>>(dist, dcol, K);
    transpose_k<<<dim3(R / 64, (KROW + 63) / 64), 256, 0, stream>>>(K, KT);
    zero_bar<<<dim3(1), 128, 0, stream>>>(bar);
    sink_k<<<dim3(NBLK), TPB, 0, stream>>>(K, KT, u, v, ctr, epb, C2, aval,
                                           1.0f / (float)C2);
    loss2_k<<<dim3(R), 256, 0, stream>>>(K, v, dist, dcol, rat2);

    final_k<<<dim3(1), 256, 0, stream>>>(rat1, rat2, out);
}

// Round 11
// 4190.060 us; speedup vs baseline: 4.6319x; 4.6319x over previous
//
#include <hip/hip_runtime.h>

#define R     8192
#define C1    8213
#define C2    8192
#define KROW  8224      // K row stride in BYTES (514 x 16B chunks, zero-padded)
#define TROW  8192      // KT row stride in BYTES (512 x 16B chunks)
#define NKC   514
#define NTC   512
#define CPF   8224      // v length in floats

typedef float f32x2 __attribute__((ext_vector_type(2)));

__device__ __forceinline__ void fp8x16_to_f(const int4 w, float f[16]) {
    f32x2 p;
    p = __builtin_amdgcn_cvt_pk_f32_fp8(w.x, false); f[0]  = p.x; f[1]  = p.y;
    p = __builtin_amdgcn_cvt_pk_f32_fp8(w.x, true);  f[2]  = p.x; f[3]  = p.y;
    p = __builtin_amdgcn_cvt_pk_f32_fp8(w.y, false); f[4]  = p.x; f[5]  = p.y;
    p = __builtin_amdgcn_cvt_pk_f32_fp8(w.y, true);  f[6]  = p.x; f[7]  = p.y;
    p = __builtin_amdgcn_cvt_pk_f32_fp8(w.z, false); f[8]  = p.x; f[9]  = p.y;
    p = __builtin_amdgcn_cvt_pk_f32_fp8(w.z, true);  f[10] = p.x; f[11] = p.y;
    p = __builtin_amdgcn_cvt_pk_f32_fp8(w.w, false); f[12] = p.x; f[13] = p.y;
    p = __builtin_amdgcn_cvt_pk_f32_fp8(w.w, true);  f[14] = p.x; f[15] = p.y;
}

__device__ __forceinline__ float fp8_to_f(int byte) {
    f32x2 p = __builtin_amdgcn_cvt_pk_f32_fp8(byte & 0xff, false);
    return p.x;
}

__device__ __forceinline__ float gm_label(float sc, int lab) {
    if (lab == 0) return fmaxf(-0.02f - sc, 0.0f) + fmaxf(sc, 0.0f);
    if (lab == 3) return fmaxf(0.09f + sc, 0.0f);
    return fmaxf(0.05f + sc, 0.0f) + fmaxf(-0.09f - sc, 0.0f); // labels 1|2
}

__device__ __forceinline__ float kval(float gm) {
    // K = exp(-M/REG), M = exp(-GM), REG = -0.2 -> exp(5*exp(-GM)); hw exp
    return __expf(5.0f * __expf(-gm));
}

__device__ __forceinline__ float dotw(const float f[16], float4 w0, float4 w1,
                                      float4 w2, float4 w3, float p) {
    p = fmaf(f[0], w0.x, p);  p = fmaf(f[1], w0.y, p);
    p = fmaf(f[2], w0.z, p);  p = fmaf(f[3], w0.w, p);
    p = fmaf(f[4], w1.x, p);  p = fmaf(f[5], w1.y, p);
    p = fmaf(f[6], w1.z, p);  p = fmaf(f[7], w1.w, p);
    p = fmaf(f[8], w2.x, p);  p = fmaf(f[9], w2.y, p);
    p = fmaf(f[10], w2.z, p); p = fmaf(f[11], w2.w, p);
    p = fmaf(f[12], w3.x, p); p = fmaf(f[13], w3.y, p);
    p = fmaf(f[14], w3.z, p); p = fmaf(f[15], w3.w, p);
    return p;
}

// ---- build kernels (R5-proven) ----

__global__ __launch_bounds__(256) void build_k1(const float* __restrict__ dist,
                                                const int* __restrict__ lab,
                                                unsigned char* __restrict__ K) {
    int row = blockIdx.y;
    int j0 = (blockIdx.x * 256 + threadIdx.x) * 4;
    if (j0 >= KROW) return;
    size_t ib = (size_t)row * C1;
    float d0 = dist[ib];
    float val[4];
#pragma unroll
    for (int k = 0; k < 4; ++k) {
        int j = j0 + k;
        val[k] = 0.0f;
        if (j < C1) {
            float g = gm_label(dist[ib + j] - d0, lab[ib + j]);
            val[k] = kval(g);
        }
    }
    int p = 0;
    p = __builtin_amdgcn_cvt_pk_fp8_f32(val[0], val[1], p, false);
    p = __builtin_amdgcn_cvt_pk_fp8_f32(val[2], val[3], p, true);
    *reinterpret_cast<int*>(K + (size_t)row * KROW + j0) = p;
}

__global__ __launch_bounds__(256) void diag_k(const float* __restrict__ dist,
                                              float* __restrict__ dcol) {
    int j = blockIdx.x * 256 + threadIdx.x;
    if (j < R) dcol[j] = dist[(size_t)j * C1 + 21 + j];
}

__global__ __launch_bounds__(256) void build_k2(const float* __restrict__ dist,
                                                const float* __restrict__ dcol,
                                                unsigned char* __restrict__ K) {
    int row = blockIdx.y;
    int j0 = (blockIdx.x * 256 + threadIdx.x) * 4;
    if (j0 >= KROW) return;
    size_t ib = (size_t)row * C1 + 21;
    float val[4];
#pragma unroll
    for (int k = 0; k < 4; ++k) {
        int j = j0 + k;
        val[k] = 0.0f;
        if (j < C2) {
            float s = dist[ib + j] - dcol[j];
            float g = (j == row) ? 0.0f : fmaxf(0.09f + s, 0.0f);
            val[k] = kval(g);
        }
    }
    int p = 0;
    p = __builtin_amdgcn_cvt_pk_fp8_f32(val[0], val[1], p, false);
    p = __builtin_amdgcn_cvt_pk_fp8_f32(val[2], val[3], p, true);
    *reinterpret_cast<int*>(K + (size_t)row * KROW + j0) = p;
}

// ---- byte transpose K[8192][KROW] -> KT[8224][TROW] via 64x64 LDS tile ----
__global__ __launch_bounds__(256) void transpose_k(const unsigned char* __restrict__ K,
                                                   unsigned char* __restrict__ KT) {
    __shared__ unsigned char tile[64][64];
    int i0 = blockIdx.x * 64;
    int j0 = blockIdx.y * 64;
    int t = threadIdx.x;
    int r = t >> 2, cb = (t & 3) << 4;
    if (j0 + cb < KROW) {
        int4 w = *reinterpret_cast<const int4*>(K + (size_t)(i0 + r) * KROW + j0 + cb);
        *reinterpret_cast<int4*>(&tile[r][cb]) = w;
    }
    __syncthreads();
    int jl = t >> 2, ib = (t & 3) << 4;
    if (j0 + jl < KROW) {
        unsigned char tmp[16];
#pragma unroll
        for (int k = 0; k < 16; ++k) tmp[k] = tile[ib + k][jl];
        *reinterpret_cast<int4*>(KT + (size_t)(j0 + jl) * TROW + i0 + ib) =
            *reinterpret_cast<const int4*>(tmp);
    }
}

__global__ __launch_bounds__(256) void fill_f(float* __restrict__ p, int n, float val) {
    int i = blockIdx.x * 256 + threadIdx.x;
    if (i < n) p[i] = val;
}

// ---- v_pass: v[j] = bval / (KT[j] . u); u staged in LDS, b128 reads;
//      wave owns 4 rows, no inner barriers; grid 514 blocks x 256 thr ----
__global__ __launch_bounds__(256) void v_pass(const unsigned char* __restrict__ KT,
                                              const float* __restrict__ u,
                                              float* __restrict__ v,
                                              int C, float bval) {
    __shared__ float ws[8192];
    int tx = threadIdx.x;
    {
        const float4* g = reinterpret_cast<const float4*>(u);
        float4* s4 = reinterpret_cast<float4*>(ws);
#pragma unroll
        for (int i = 0; i < 8; ++i) s4[tx + i * 256] = g[tx + i * 256];
    }
    __syncthreads();
    int lane = tx & 63, wv = tx >> 6;
    const int4* KTb = reinterpret_cast<const int4*>(KT);
    const float4* w4 = reinterpret_cast<const float4*>(ws);
    int rbase = blockIdx.x * 16 + wv * 4;
#pragma unroll
    for (int rr = 0; rr < 4; ++rr) {
        int row = rbase + rr;                    // 0..8223
        const int4* Kr = KTb + (size_t)row * NTC;
        float p = 0.0f;
#pragma unroll
        for (int s = 0; s < 8; ++s) {
            int ch = s * 64 + lane;
            float f[16];
            fp8x16_to_f(Kr[ch], f);
            p = dotw(f, w4[ch * 4], w4[ch * 4 + 1], w4[ch * 4 + 2], w4[ch * 4 + 3], p);
        }
#pragma unroll
        for (int off = 32; off; off >>= 1) p += __shfl_down(p, off, 64);
        if (lane == 0) v[row] = (row < C) ? bval / p : 0.0f;
    }
}

// ---- u_pass: u[i] = aval / (K[i] . v); v staged in LDS (8224 floats);
//      wave owns 4 rows; grid 512 blocks x 256 thr ----
__global__ __launch_bounds__(256) void u_pass(const unsigned char* __restrict__ K,
                                              const float* __restrict__ v,
                                              float* __restrict__ u, float aval) {
    __shared__ float ws[CPF];
    int tx = threadIdx.x;
    {
        const float4* g = reinterpret_cast<const float4*>(v);
        float4* s4 = reinterpret_cast<float4*>(ws);
#pragma unroll
        for (int i = 0; i < 8; ++i) s4[tx + i * 256] = g[tx + i * 256];
        if (tx < 8) s4[2048 + tx] = g[2048 + tx];
    }
    __syncthreads();
    int lane = tx & 63, wv = tx >> 6;
    const int4* Kb = reinterpret_cast<const int4*>(K);
    const float4* w4 = reinterpret_cast<const float4*>(ws);
    int rbase = blockIdx.x * 16 + wv * 4;
#pragma unroll
    for (int rr = 0; rr < 4; ++rr) {
        int row = rbase + rr;
        const int4* Kr = Kb + (size_t)row * NKC;
        float p = 0.0f;
#pragma unroll
        for (int s = 0; s < 8; ++s) {
            int ch = s * 64 + lane;
            float f[16];
            fp8x16_to_f(Kr[ch], f);
            p = dotw(f, w4[ch * 4], w4[ch * 4 + 1], w4[ch * 4 + 2], w4[ch * 4 + 3], p);
        }
        if (lane < 2) {                          // tail chunks 512, 513
            int ch = 512 + lane;
            float f[16];
            fp8x16_to_f(Kr[ch], f);
            p = dotw(f, w4[ch * 4], w4[ch * 4 + 1], w4[ch * 4 + 2], w4[ch * 4 + 3], p);
        }
#pragma unroll
        for (int off = 32; off; off >>= 1) p += __shfl_down(p, off, 64);
        if (lane == 0) u[row] = aval / p;
    }
}

// ---- loss reductions (R5-proven) ----

__device__ __forceinline__ float2 block_reduce_2(float x, float y, float* sb) {
#pragma unroll
    for (int off = 32; off; off >>= 1) {
        x += __shfl_down(x, off, 64);
        y += __shfl_down(y, off, 64);
    }
    if ((threadIdx.x & 63) == 0) {
        int w = threadIdx.x >> 6;
        sb[w] = x; sb[4 + w] = y;
    }
    __syncthreads();
    float2 r;
    r.x = sb[0] + sb[1] + sb[2] + sb[3];
    r.y = sb[4] + sb[5] + sb[6] + sb[7];
    __syncthreads();
    return r;
}

__global__ __launch_bounds__(256) void loss1_k(const unsigned char* __restrict__ K,
                                               const float* __restrict__ v,
                                               const float* __restrict__ dist,
                                               const int* __restrict__ lab,
                                               float* __restrict__ ratio) {
    __shared__ float sb[8];
    int i = blockIdx.x;
    size_t ib = (size_t)i * C1;
    float d0 = dist[ib];
    const unsigned char* Kr = K + (size_t)i * KROW;
    float num = 0, den = 0;
    for (int j0 = threadIdx.x * 4; j0 < C1; j0 += 1024) {
        int p = *reinterpret_cast<const int*>(Kr + j0);
#pragma unroll
        for (int k = 0; k < 4; ++k) {
            int j = j0 + k;
            int jc = (j < C1) ? j : (C1 - 1);
            float kv = fp8_to_f(p >> (k * 8)) * v[jc];   // K pad = 0 -> kv = 0 beyond C1
            float g = gm_label(dist[ib + jc] - d0, lab[ib + jc]);
            den += kv;
            num = fmaf(g, kv, num);
        }
    }
    float2 r = block_reduce_2(num, den, sb);
    if (threadIdx.x == 0) ratio[i] = r.x / r.y;
}

__global__ __launch_bounds__(256) void loss2_k(const unsigned char* __restrict__ K,
                                               const float* __restrict__ v,
                                               const float* __restrict__ dist,
                                               const float* __restrict__ dcol,
                                               float* __restrict__ ratio) {
    __shared__ float sb[8];
    int i = blockIdx.x;
    const unsigned char* Kr = K + (size_t)i * KROW;
    const float* Dr = dist + (size_t)i * C1 + 21;
    float num = 0, den = 0;
    for (int j0 = threadIdx.x * 4; j0 < C2; j0 += 1024) {
        int p = *reinterpret_cast<const int*>(Kr + j0);
#pragma unroll
        for (int k = 0; k < 4; ++k) {
            int j = j0 + k;
            if (j == i) continue;
            float kv = fp8_to_f(p >> (k * 8)) * v[j];
            float h = fmaxf(0.09f + Dr[j] - dcol[j], 0.0f);
            den += kv;
            num = fmaf(h, kv, num);
        }
    }
    float2 r = block_reduce_2(num, den, sb);
    if (threadIdx.x == 0) ratio[i] = r.x / r.y;
}

__global__ __launch_bounds__(256) void final_k(const float* __restrict__ r1,
                                               const float* __restrict__ r2,
                                               float* __restrict__ out) {
    __shared__ float sb[8];
    float s1 = 0, s2 = 0;
    for (int i = threadIdx.x; i < R; i += 256) { s1 += r1[i]; s2 += r2[i]; }
    float2 t = block_reduce_2(s1, s2, sb);
    if (threadIdx.x == 0)
        out[0] = t.x / ((float)R * (float)C1) + t.y / ((float)R * (float)C2);
}

static void run_phase(const unsigned char* K, const unsigned char* KT,
                      float* u, float* v, int C, hipStream_t stream) {
    float aval = 1.0f / (float)R;
    float bval = 1.0f / (float)C;
    fill_f<<<dim3(R / 256), 256, 0, stream>>>(u, R, aval);
    for (int t = 0; t < 50; ++t) {
        v_pass<<<dim3(CPF / 16), 256, 0, stream>>>(KT, u, v, C, bval);
        if (t < 49)
            u_pass<<<dim3(R / 16), 256, 0, stream>>>(K, v, u, aval);
    }
}

extern "C" void kernel_launch(void* const* d_in, const int* in_sizes, int n_in,
                              void* d_out, int out_size, void* d_ws, size_t ws_size,
                              hipStream_t stream) {
    const float* dist = (const float*)d_in[0];
    const int* lab = (const int*)d_in[1];
    float* out = (float*)d_out;
    char* ws = (char*)d_ws;

    size_t need = (size_t)R * KROW                       // K (fp8)
                + (size_t)KROW * TROW                    // KT (fp8)
                + (size_t)CPF * sizeof(float)            // v
                + 4 * (size_t)R * sizeof(float);         // u, dcol, rat1, rat2
    if (ws_size < need) return;

    size_t off = 0;
    unsigned char* K = (unsigned char*)(ws + off);  off += (size_t)R * KROW;
    unsigned char* KT = (unsigned char*)(ws + off); off += (size_t)KROW * TROW;
    float* v = (float*)(ws + off);     off += (size_t)CPF * sizeof(float);
    float* u = (float*)(ws + off);     off += (size_t)R * sizeof(float);
    float* dcol = (float*)(ws + off);  off += (size_t)R * sizeof(float);
    float* rat1 = (float*)(ws + off);  off += (size_t)R * sizeof(float);
    float* rat2 = (float*)(ws + off);  off += (size_t)R * sizeof(float);

    int gb = (KROW / 4 + 255) / 256;   // 9 blocks per row

    // ---- phase 1 ----
    build_k1<<<dim3(gb, R), 256, 0, stream>>>(dist, lab, K);
    transpose_k<<<dim3(R / 64, (KROW + 63) / 64), 256, 0, stream>>>(K, KT);
    run_phase(K, KT, u, v, C1, stream);
    loss1_k<<<dim3(R), 256, 0, stream>>>(K, v, dist, lab, rat1);

    // ---- phase 2 (reuses K and KT buffers) ----
    diag_k<<<dim3(R / 256), 256, 0, stream>>>(dist, dcol);
    build_k2<<<dim3(gb, R), 256, 0, stream>>>(dist, dcol, K);
    transpose_k<<<dim3(R / 64, (KROW + 63) / 64), 256, 0, stream>>>(K, KT);
    run_phase(K, KT, u, v, C2, stream);
    loss2_k<<<dim3(R), 256, 0, stream>>>(K, v, dist, dcol, rat2);

    final_k<<<dim3(1), 256, 0, stream>>>(rat1, rat2, out);
}

// Round 12
// 3418.727 us; speedup vs baseline: 5.6770x; 1.2256x over previous
//
#include <hip/hip_runtime.h>

#define R     8192
#define C1    8213
#define C2    8192
#define KROW  8224      // K/GM row stride in BYTES (514 x 16B chunks, zero-padded)
#define TROW  8192      // KT row stride in BYTES (512 x 16B chunks)
#define NKC   514
#define NTC   512
#define CPF   8224      // v length in floats

typedef float f32x2 __attribute__((ext_vector_type(2)));

__device__ __forceinline__ void fp8x16_to_f(const int4 w, float f[16]) {
    f32x2 p;
    p = __builtin_amdgcn_cvt_pk_f32_fp8(w.x, false); f[0]  = p.x; f[1]  = p.y;
    p = __builtin_amdgcn_cvt_pk_f32_fp8(w.x, true);  f[2]  = p.x; f[3]  = p.y;
    p = __builtin_amdgcn_cvt_pk_f32_fp8(w.y, false); f[4]  = p.x; f[5]  = p.y;
    p = __builtin_amdgcn_cvt_pk_f32_fp8(w.y, true);  f[6]  = p.x; f[7]  = p.y;
    p = __builtin_amdgcn_cvt_pk_f32_fp8(w.z, false); f[8]  = p.x; f[9]  = p.y;
    p = __builtin_amdgcn_cvt_pk_f32_fp8(w.z, true);  f[10] = p.x; f[11] = p.y;
    p = __builtin_amdgcn_cvt_pk_f32_fp8(w.w, false); f[12] = p.x; f[13] = p.y;
    p = __builtin_amdgcn_cvt_pk_f32_fp8(w.w, true);  f[14] = p.x; f[15] = p.y;
}

__device__ __forceinline__ float fp8_to_f(int byte) {
    f32x2 p = __builtin_amdgcn_cvt_pk_f32_fp8(byte & 0xff, false);
    return p.x;
}

__device__ __forceinline__ float gm_label(float sc, int lab) {
    if (lab == 0) return fmaxf(-0.02f - sc, 0.0f) + fmaxf(sc, 0.0f);
    if (lab == 3) return fmaxf(0.09f + sc, 0.0f);
    return fmaxf(0.05f + sc, 0.0f) + fmaxf(-0.09f - sc, 0.0f); // labels 1|2
}

__device__ __forceinline__ float kval(float gm) {
    // K = exp(-M/REG), M = exp(-GM), REG = -0.2 -> exp(5*exp(-GM)); hw exp
    return __expf(5.0f * __expf(-gm));
}

__device__ __forceinline__ float dotw(const float f[16], float4 w0, float4 w1,
                                      float4 w2, float4 w3, float p) {
    p = fmaf(f[0], w0.x, p);  p = fmaf(f[1], w0.y, p);
    p = fmaf(f[2], w0.z, p);  p = fmaf(f[3], w0.w, p);
    p = fmaf(f[4], w1.x, p);  p = fmaf(f[5], w1.y, p);
    p = fmaf(f[6], w1.z, p);  p = fmaf(f[7], w1.w, p);
    p = fmaf(f[8], w2.x, p);  p = fmaf(f[9], w2.y, p);
    p = fmaf(f[10], w2.z, p); p = fmaf(f[11], w2.w, p);
    p = fmaf(f[12], w3.x, p); p = fmaf(f[13], w3.y, p);
    p = fmaf(f[14], w3.z, p); p = fmaf(f[15], w3.w, p);
    return p;
}

// ---- build kernels (R2/R5-proven layout) + optional fp8 GM store ----

__global__ __launch_bounds__(256) void build_k1(const float* __restrict__ dist,
                                                const int* __restrict__ lab,
                                                unsigned char* __restrict__ K,
                                                unsigned char* __restrict__ gm) {
    int row = blockIdx.y;
    int j0 = (blockIdx.x * 256 + threadIdx.x) * 4;
    if (j0 >= KROW) return;
    size_t ib = (size_t)row * C1;
    float d0 = dist[ib];
    float val[4], gv[4];
#pragma unroll
    for (int k = 0; k < 4; ++k) {
        int j = j0 + k;
        val[k] = 0.0f; gv[k] = 0.0f;
        if (j < C1) {
            float g = gm_label(dist[ib + j] - d0, lab[ib + j]);
            gv[k] = g;
            val[k] = kval(g);
        }
    }
    int p = 0;
    p = __builtin_amdgcn_cvt_pk_fp8_f32(val[0], val[1], p, false);
    p = __builtin_amdgcn_cvt_pk_fp8_f32(val[2], val[3], p, true);
    *reinterpret_cast<int*>(K + (size_t)row * KROW + j0) = p;
    if (gm) {
        int q = 0;
        q = __builtin_amdgcn_cvt_pk_fp8_f32(gv[0], gv[1], q, false);
        q = __builtin_amdgcn_cvt_pk_fp8_f32(gv[2], gv[3], q, true);
        *reinterpret_cast<int*>(gm + (size_t)row * KROW + j0) = q;
    }
}

__global__ __launch_bounds__(256) void diag_k(const float* __restrict__ dist,
                                              float* __restrict__ dcol) {
    int j = blockIdx.x * 256 + threadIdx.x;
    if (j < R) dcol[j] = dist[(size_t)j * C1 + 21 + j];
}

__global__ __launch_bounds__(256) void build_k2(const float* __restrict__ dist,
                                                const float* __restrict__ dcol,
                                                unsigned char* __restrict__ K,
                                                unsigned char* __restrict__ gm) {
    int row = blockIdx.y;
    int j0 = (blockIdx.x * 256 + threadIdx.x) * 4;
    if (j0 >= KROW) return;
    size_t ib = (size_t)row * C1 + 21;
    float val[4], gv[4];
#pragma unroll
    for (int k = 0; k < 4; ++k) {
        int j = j0 + k;
        val[k] = 0.0f; gv[k] = 0.0f;
        if (j < C2) {
            float s = dist[ib + j] - dcol[j];
            float g = (j == row) ? 0.0f : fmaxf(0.09f + s, 0.0f);
            gv[k] = g;
            val[k] = kval(g);
        }
    }
    int p = 0;
    p = __builtin_amdgcn_cvt_pk_fp8_f32(val[0], val[1], p, false);
    p = __builtin_amdgcn_cvt_pk_fp8_f32(val[2], val[3], p, true);
    *reinterpret_cast<int*>(K + (size_t)row * KROW + j0) = p;
    if (gm) {
        int q = 0;
        q = __builtin_amdgcn_cvt_pk_fp8_f32(gv[0], gv[1], q, false);
        q = __builtin_amdgcn_cvt_pk_fp8_f32(gv[2], gv[3], q, true);
        *reinterpret_cast<int*>(gm + (size_t)row * KROW + j0) = q;
    }
}

// ---- byte transpose K[8192][KROW] -> KT[8224][TROW] via 64x64 LDS tile ----
__global__ __launch_bounds__(256) void transpose_k(const unsigned char* __restrict__ K,
                                                   unsigned char* __restrict__ KT) {
    __shared__ unsigned char tile[64][64];
    int i0 = blockIdx.x * 64;
    int j0 = blockIdx.y * 64;
    int t = threadIdx.x;
    int r = t >> 2, cb = (t & 3) << 4;
    if (j0 + cb < KROW) {
        int4 w = *reinterpret_cast<const int4*>(K + (size_t)(i0 + r) * KROW + j0 + cb);
        *reinterpret_cast<int4*>(&tile[r][cb]) = w;
    }
    __syncthreads();
    int jl = t >> 2, ib = (t & 3) << 4;
    if (j0 + jl < KROW) {
        unsigned char tmp[16];
#pragma unroll
        for (int k = 0; k < 16; ++k) tmp[k] = tile[ib + k][jl];
        *reinterpret_cast<int4*>(KT + (size_t)(j0 + jl) * TROW + i0 + ib) =
            *reinterpret_cast<const int4*>(tmp);
    }
}

__global__ __launch_bounds__(256) void fill_f(float* __restrict__ p, int n, float val) {
    int i = blockIdx.x * 256 + threadIdx.x;
    if (i < n) p[i] = val;
}

// ---- v_pass: v[j] = bval / (KT[j] . u); u in LDS; 2 rows per wave;
//      grid 1028 blocks x 256 thr (4 blocks/CU, 16 waves/CU) ----
__global__ __launch_bounds__(256) void v_pass(const unsigned char* __restrict__ KT,
                                              const float* __restrict__ u,
                                              float* __restrict__ v,
                                              int C, float bval) {
    __shared__ float ws[8192];
    int tx = threadIdx.x;
    {
        const float4* g = reinterpret_cast<const float4*>(u);
        float4* s4 = reinterpret_cast<float4*>(ws);
        s4[tx] = g[tx];
        s4[tx + 256] = g[tx + 256];
    }
    __syncthreads();
    int lane = tx & 63, wv = tx >> 6;
    const int4* KTb = reinterpret_cast<const int4*>(KT);
    const float4* w4 = reinterpret_cast<const float4*>(ws);
    int ra = blockIdx.x * 8 + wv * 2;
    const int4* K0 = KTb + (size_t)ra * NTC;
    const int4* K1 = K0 + NTC;
    float p0 = 0.0f, p1 = 0.0f;
#pragma unroll
    for (int s = 0; s < 8; ++s) {
        int ch = s * 64 + lane;
        float4 w0 = w4[ch * 4], w1 = w4[ch * 4 + 1];
        float4 w2 = w4[ch * 4 + 2], w3 = w4[ch * 4 + 3];
        float f[16];
        fp8x16_to_f(K0[ch], f);
        p0 = dotw(f, w0, w1, w2, w3, p0);
        fp8x16_to_f(K1[ch], f);
        p1 = dotw(f, w0, w1, w2, w3, p1);
    }
#pragma unroll
    for (int off = 32; off; off >>= 1) {
        p0 += __shfl_down(p0, off, 64);
        p1 += __shfl_down(p1, off, 64);
    }
    if (lane == 0) {
        v[ra]     = (ra < C)     ? bval / p0 : 0.0f;
        v[ra + 1] = (ra + 1 < C) ? bval / p1 : 0.0f;
    }
}

// ---- u_pass: u[i] = aval / (K[i] . v); v in LDS; 2 rows per wave;
//      grid 1024 blocks x 256 thr ----
__global__ __launch_bounds__(256) void u_pass(const unsigned char* __restrict__ K,
                                              const float* __restrict__ v,
                                              float* __restrict__ u, float aval) {
    __shared__ float ws[CPF];
    int tx = threadIdx.x;
    {
        const float4* g = reinterpret_cast<const float4*>(v);
        float4* s4 = reinterpret_cast<float4*>(ws);
#pragma unroll
        for (int i = 0; i < 8; ++i) s4[tx + i * 256] = g[tx + i * 256];
        if (tx < 8) s4[2048 + tx] = g[2048 + tx];
    }
    __syncthreads();
    int lane = tx & 63, wv = tx >> 6;
    const int4* Kb = reinterpret_cast<const int4*>(K);
    const float4* w4 = reinterpret_cast<const float4*>(ws);
    int ra = blockIdx.x * 8 + wv * 2;
    const int4* K0 = Kb + (size_t)ra * NKC;
    const int4* K1 = K0 + NKC;
    float p0 = 0.0f, p1 = 0.0f;
#pragma unroll
    for (int s = 0; s < 8; ++s) {
        int ch = s * 64 + lane;
        float4 w0 = w4[ch * 4], w1 = w4[ch * 4 + 1];
        float4 w2 = w4[ch * 4 + 2], w3 = w4[ch * 4 + 3];
        float f[16];
        fp8x16_to_f(K0[ch], f);
        p0 = dotw(f, w0, w1, w2, w3, p0);
        fp8x16_to_f(K1[ch], f);
        p1 = dotw(f, w0, w1, w2, w3, p1);
    }
    if (lane < 2) {                          // tail chunks 512, 513
        int ch = 512 + lane;
        float4 w0 = w4[ch * 4], w1 = w4[ch * 4 + 1];
        float4 w2 = w4[ch * 4 + 2], w3 = w4[ch * 4 + 3];
        float f[16];
        fp8x16_to_f(K0[ch], f);
        p0 = dotw(f, w0, w1, w2, w3, p0);
        fp8x16_to_f(K1[ch], f);
        p1 = dotw(f, w0, w1, w2, w3, p1);
    }
#pragma unroll
    for (int off = 32; off; off >>= 1) {
        p0 += __shfl_down(p0, off, 64);
        p1 += __shfl_down(p1, off, 64);
    }
    if (lane == 0) {
        u[ra]     = aval / p0;
        u[ra + 1] = aval / p1;
    }
}

// ---- loss reductions ----

__device__ __forceinline__ float2 block_reduce_2(float x, float y, float* sb) {
#pragma unroll
    for (int off = 32; off; off >>= 1) {
        x += __shfl_down(x, off, 64);
        y += __shfl_down(y, off, 64);
    }
    if ((threadIdx.x & 63) == 0) {
        int w = threadIdx.x >> 6;
        sb[w] = x; sb[4 + w] = y;
    }
    __syncthreads();
    float2 r;
    r.x = sb[0] + sb[1] + sb[2] + sb[3];
    r.y = sb[4] + sb[5] + sb[6] + sb[7];
    __syncthreads();
    return r;
}

// GM-path losses: read fp8 K + fp8 GM only (no dist/labels)
__global__ __launch_bounds__(256) void loss1_gm(const unsigned char* __restrict__ K,
                                                const unsigned char* __restrict__ GM,
                                                const float* __restrict__ v,
                                                float* __restrict__ ratio) {
    __shared__ float sb[8];
    int i = blockIdx.x;
    const int4* Kr = reinterpret_cast<const int4*>(K + (size_t)i * KROW);
    const int4* Gr = reinterpret_cast<const int4*>(GM + (size_t)i * KROW);
    const float4* v4 = reinterpret_cast<const float4*>(v);
    float num = 0, den = 0;
    for (int c = threadIdx.x; c < NKC; c += 256) {
        float kf[16], gf[16];
        fp8x16_to_f(Kr[c], kf);
        fp8x16_to_f(Gr[c], gf);
#pragma unroll
        for (int q = 0; q < 4; ++q) {
            float4 w = v4[c * 4 + q];
            float k0 = kf[q * 4 + 0] * w.x, k1 = kf[q * 4 + 1] * w.y;
            float k2 = kf[q * 4 + 2] * w.z, k3 = kf[q * 4 + 3] * w.w;
            den += k0 + k1 + k2 + k3;
            num = fmaf(gf[q * 4 + 0], k0, num);
            num = fmaf(gf[q * 4 + 1], k1, num);
            num = fmaf(gf[q * 4 + 2], k2, num);
            num = fmaf(gf[q * 4 + 3], k3, num);
        }
    }
    float2 r = block_reduce_2(num, den, sb);
    if (threadIdx.x == 0) ratio[i] = r.x / r.y;
}

__global__ __launch_bounds__(256) void loss2_gm(const unsigned char* __restrict__ K,
                                                const unsigned char* __restrict__ GM,
                                                const float* __restrict__ v,
                                                float* __restrict__ ratio) {
    __shared__ float sb[8];
    int i = blockIdx.x;
    const int4* Kr = reinterpret_cast<const int4*>(K + (size_t)i * KROW);
    const int4* Gr = reinterpret_cast<const int4*>(GM + (size_t)i * KROW);
    const float4* v4 = reinterpret_cast<const float4*>(v);
    float num = 0, den = 0;
    for (int c = threadIdx.x; c < NKC; c += 256) {
        float kf[16], gf[16];
        fp8x16_to_f(Kr[c], kf);
        fp8x16_to_f(Gr[c], gf);
        int jb = c * 16;
#pragma unroll
        for (int q = 0; q < 4; ++q) {
            float4 w = v4[c * 4 + q];
            float m0 = (jb + q * 4 + 0 == i) ? 0.0f : 1.0f;
            float m1 = (jb + q * 4 + 1 == i) ? 0.0f : 1.0f;
            float m2 = (jb + q * 4 + 2 == i) ? 0.0f : 1.0f;
            float m3 = (jb + q * 4 + 3 == i) ? 0.0f : 1.0f;
            float k0 = kf[q * 4 + 0] * w.x * m0, k1 = kf[q * 4 + 1] * w.y * m1;
            float k2 = kf[q * 4 + 2] * w.z * m2, k3 = kf[q * 4 + 3] * w.w * m3;
            den += k0 + k1 + k2 + k3;
            num = fmaf(gf[q * 4 + 0], k0, num);
            num = fmaf(gf[q * 4 + 1], k1, num);
            num = fmaf(gf[q * 4 + 2], k2, num);
            num = fmaf(gf[q * 4 + 3], k3, num);
        }
    }
    float2 r = block_reduce_2(num, den, sb);
    if (threadIdx.x == 0) ratio[i] = r.x / r.y;
}

// Fallback losses (R11-proven, no GM buffer)
__global__ __launch_bounds__(256) void loss1_k(const unsigned char* __restrict__ K,
                                               const float* __restrict__ v,
                                               const float* __restrict__ dist,
                                               const int* __restrict__ lab,
                                               float* __restrict__ ratio) {
    __shared__ float sb[8];
    int i = blockIdx.x;
    size_t ib = (size_t)i * C1;
    float d0 = dist[ib];
    const unsigned char* Kr = K + (size_t)i * KROW;
    float num = 0, den = 0;
    for (int j0 = threadIdx.x * 4; j0 < C1; j0 += 1024) {
        int p = *reinterpret_cast<const int*>(Kr + j0);
#pragma unroll
        for (int k = 0; k < 4; ++k) {
            int j = j0 + k;
            int jc = (j < C1) ? j : (C1 - 1);
            float kv = fp8_to_f(p >> (k * 8)) * v[jc];
            float g = gm_label(dist[ib + jc] - d0, lab[ib + jc]);
            den += kv;
            num = fmaf(g, kv, num);
        }
    }
    float2 r = block_reduce_2(num, den, sb);
    if (threadIdx.x == 0) ratio[i] = r.x / r.y;
}

__global__ __launch_bounds__(256) void loss2_k(const unsigned char* __restrict__ K,
                                               const float* __restrict__ v,
                                               const float* __restrict__ dist,
                                               const float* __restrict__ dcol,
                                               float* __restrict__ ratio) {
    __shared__ float sb[8];
    int i = blockIdx.x;
    const unsigned char* Kr = K + (size_t)i * KROW;
    const float* Dr = dist + (size_t)i * C1 + 21;
    float num = 0, den = 0;
    for (int j0 = threadIdx.x * 4; j0 < C2; j0 += 1024) {
        int p = *reinterpret_cast<const int*>(Kr + j0);
#pragma unroll
        for (int k = 0; k < 4; ++k) {
            int j = j0 + k;
            if (j == i) continue;
            float kv = fp8_to_f(p >> (k * 8)) * v[j];
            float h = fmaxf(0.09f + Dr[j] - dcol[j], 0.0f);
            den += kv;
            num = fmaf(h, kv, num);
        }
    }
    float2 r = block_reduce_2(num, den, sb);
    if (threadIdx.x == 0) ratio[i] = r.x / r.y;
}

__global__ __launch_bounds__(256) void final_k(const float* __restrict__ r1,
                                               const float* __restrict__ r2,
                                               float* __restrict__ out) {
    __shared__ float sb[8];
    float s1 = 0, s2 = 0;
    for (int i = threadIdx.x; i < R; i += 256) { s1 += r1[i]; s2 += r2[i]; }
    float2 t = block_reduce_2(s1, s2, sb);
    if (threadIdx.x == 0)
        out[0] = t.x / ((float)R * (float)C1) + t.y / ((float)R * (float)C2);
}

static void run_phase(const unsigned char* K, const unsigned char* KT,
                      float* u, float* v, int C, hipStream_t stream) {
    float aval = 1.0f / (float)R;
    float bval = 1.0f / (float)C;
    fill_f<<<dim3(R / 256), 256, 0, stream>>>(u, R, aval);
    for (int t = 0; t < 50; ++t) {
        v_pass<<<dim3(CPF / 8), 256, 0, stream>>>(KT, u, v, C, bval);
        if (t < 49)
            u_pass<<<dim3(R / 8), 256, 0, stream>>>(K, v, u, aval);
    }
}

extern "C" void kernel_launch(void* const* d_in, const int* in_sizes, int n_in,
                              void* d_out, int out_size, void* d_ws, size_t ws_size,
                              hipStream_t stream) {
    const float* dist = (const float*)d_in[0];
    const int* lab = (const int*)d_in[1];
    float* out = (float*)d_out;
    char* ws = (char*)d_ws;

    const size_t kbytes = (size_t)R * KROW;   // 67,371,008
    const size_t tbytes = (size_t)KROW * TROW;
    size_t small = (size_t)CPF * sizeof(float) + 4 * (size_t)R * sizeof(float);
    size_t need_base = kbytes + tbytes + small;
    size_t need_gm = need_base + kbytes;
    if (ws_size < need_base) return;
    bool useGM = ws_size >= need_gm;

    size_t off = 0;
    unsigned char* K = (unsigned char*)(ws + off);  off += kbytes;
    unsigned char* KT = (unsigned char*)(ws + off); off += tbytes;
    unsigned char* GM = nullptr;
    if (useGM) { GM = (unsigned char*)(ws + off); off += kbytes; }
    float* v = (float*)(ws + off);     off += (size_t)CPF * sizeof(float);
    float* u = (float*)(ws + off);     off += (size_t)R * sizeof(float);
    float* dcol = (float*)(ws + off);  off += (size_t)R * sizeof(float);
    float* rat1 = (float*)(ws + off);  off += (size_t)R * sizeof(float);
    float* rat2 = (float*)(ws + off);  off += (size_t)R * sizeof(float);

    int gb = (KROW / 4 + 255) / 256;   // 9 blocks per row

    // ---- phase 1 ----
    build_k1<<<dim3(gb, R), 256, 0, stream>>>(dist, lab, K, GM);
    transpose_k<<<dim3(R / 64, (KROW + 63) / 64), 256, 0, stream>>>(K, KT);
    run_phase(K, KT, u, v, C1, stream);
    if (useGM)
        loss1_gm<<<dim3(R), 256, 0, stream>>>(K, GM, v, rat1);
    else
        loss1_k<<<dim3(R), 256, 0, stream>>>(K, v, dist, lab, rat1);

    // ---- phase 2 (reuses K and KT buffers) ----
    diag_k<<<dim3(R / 256), 256, 0, stream>>>(dist, dcol);
    build_k2<<<dim3(gb, R), 256, 0, stream>>>(dist, dcol, K, GM);
    transpose_k<<<dim3(R / 64, (KROW + 63) / 64), 256, 0, stream>>>(K, KT);
    run_phase(K, KT, u, v, C2, stream);
    if (useGM)
        loss2_gm<<<dim3(R), 256, 0, stream>>>(K, GM, v, rat2);
    else
        loss2_k<<<dim3(R), 256, 0, stream>>>(K, v, dist, dcol, rat2);

    final_k<<<dim3(1), 256, 0, stream>>>(rat1, rat2, out);
}

// Round 13
// 3371.088 us; speedup vs baseline: 5.7572x; 1.0141x over previous
//
#include <hip/hip_runtime.h>

#define R     8192
#define C1    8213
#define C2    8192
#define KROW  8224      // K/GM row stride in BYTES (514 x 16B chunks, zero-padded)
#define TROW  8192      // KT row stride in BYTES (512 x 16B chunks)
#define NKC   514
#define NTC   512
#define CPF   8224      // v length in floats

typedef float f32x2 __attribute__((ext_vector_type(2)));

__device__ __forceinline__ void fp8x16_to_f(const int4 w, float f[16]) {
    f32x2 p;
    p = __builtin_amdgcn_cvt_pk_f32_fp8(w.x, false); f[0]  = p.x; f[1]  = p.y;
    p = __builtin_amdgcn_cvt_pk_f32_fp8(w.x, true);  f[2]  = p.x; f[3]  = p.y;
    p = __builtin_amdgcn_cvt_pk_f32_fp8(w.y, false); f[4]  = p.x; f[5]  = p.y;
    p = __builtin_amdgcn_cvt_pk_f32_fp8(w.y, true);  f[6]  = p.x; f[7]  = p.y;
    p = __builtin_amdgcn_cvt_pk_f32_fp8(w.z, false); f[8]  = p.x; f[9]  = p.y;
    p = __builtin_amdgcn_cvt_pk_f32_fp8(w.z, true);  f[10] = p.x; f[11] = p.y;
    p = __builtin_amdgcn_cvt_pk_f32_fp8(w.w, false); f[12] = p.x; f[13] = p.y;
    p = __builtin_amdgcn_cvt_pk_f32_fp8(w.w, true);  f[14] = p.x; f[15] = p.y;
}

__device__ __forceinline__ float fp8_to_f(int byte) {
    f32x2 p = __builtin_amdgcn_cvt_pk_f32_fp8(byte & 0xff, false);
    return p.x;
}

__device__ __forceinline__ float gm_label(float sc, int lab) {
    if (lab == 0) return fmaxf(-0.02f - sc, 0.0f) + fmaxf(sc, 0.0f);
    if (lab == 3) return fmaxf(0.09f + sc, 0.0f);
    return fmaxf(0.05f + sc, 0.0f) + fmaxf(-0.09f - sc, 0.0f); // labels 1|2
}

__device__ __forceinline__ float kval(float gm) {
    // K = exp(-M/REG), M = exp(-GM), REG = -0.2 -> exp(5*exp(-GM)); hw exp
    return __expf(5.0f * __expf(-gm));
}

__device__ __forceinline__ float dotw(const float f[16], float4 w0, float4 w1,
                                      float4 w2, float4 w3, float p) {
    p = fmaf(f[0], w0.x, p);  p = fmaf(f[1], w0.y, p);
    p = fmaf(f[2], w0.z, p);  p = fmaf(f[3], w0.w, p);
    p = fmaf(f[4], w1.x, p);  p = fmaf(f[5], w1.y, p);
    p = fmaf(f[6], w1.z, p);  p = fmaf(f[7], w1.w, p);
    p = fmaf(f[8], w2.x, p);  p = fmaf(f[9], w2.y, p);
    p = fmaf(f[10], w2.z, p); p = fmaf(f[11], w2.w, p);
    p = fmaf(f[12], w3.x, p); p = fmaf(f[13], w3.y, p);
    p = fmaf(f[14], w3.z, p); p = fmaf(f[15], w3.w, p);
    return p;
}

// ---- build kernels (R2/R5-proven layout) + optional fp8 GM store ----

__global__ __launch_bounds__(256) void build_k1(const float* __restrict__ dist,
                                                const int* __restrict__ lab,
                                                unsigned char* __restrict__ K,
                                                unsigned char* __restrict__ gm) {
    int row = blockIdx.y;
    int j0 = (blockIdx.x * 256 + threadIdx.x) * 4;
    if (j0 >= KROW) return;
    size_t ib = (size_t)row * C1;
    float d0 = dist[ib];
    float val[4], gv[4];
#pragma unroll
    for (int k = 0; k < 4; ++k) {
        int j = j0 + k;
        val[k] = 0.0f; gv[k] = 0.0f;
        if (j < C1) {
            float g = gm_label(dist[ib + j] - d0, lab[ib + j]);
            gv[k] = g;
            val[k] = kval(g);
        }
    }
    int p = 0;
    p = __builtin_amdgcn_cvt_pk_fp8_f32(val[0], val[1], p, false);
    p = __builtin_amdgcn_cvt_pk_fp8_f32(val[2], val[3], p, true);
    *reinterpret_cast<int*>(K + (size_t)row * KROW + j0) = p;
    if (gm) {
        int q = 0;
        q = __builtin_amdgcn_cvt_pk_fp8_f32(gv[0], gv[1], q, false);
        q = __builtin_amdgcn_cvt_pk_fp8_f32(gv[2], gv[3], q, true);
        *reinterpret_cast<int*>(gm + (size_t)row * KROW + j0) = q;
    }
}

__global__ __launch_bounds__(256) void diag_k(const float* __restrict__ dist,
                                              float* __restrict__ dcol) {
    int j = blockIdx.x * 256 + threadIdx.x;
    if (j < R) dcol[j] = dist[(size_t)j * C1 + 21 + j];
}

__global__ __launch_bounds__(256) void build_k2(const float* __restrict__ dist,
                                                const float* __restrict__ dcol,
                                                unsigned char* __restrict__ K,
                                                unsigned char* __restrict__ gm) {
    int row = blockIdx.y;
    int j0 = (blockIdx.x * 256 + threadIdx.x) * 4;
    if (j0 >= KROW) return;
    size_t ib = (size_t)row * C1 + 21;
    float val[4], gv[4];
#pragma unroll
    for (int k = 0; k < 4; ++k) {
        int j = j0 + k;
        val[k] = 0.0f; gv[k] = 0.0f;
        if (j < C2) {
            float s = dist[ib + j] - dcol[j];
            float g = (j == row) ? 0.0f : fmaxf(0.09f + s, 0.0f);
            gv[k] = g;
            val[k] = kval(g);
        }
    }
    int p = 0;
    p = __builtin_amdgcn_cvt_pk_fp8_f32(val[0], val[1], p, false);
    p = __builtin_amdgcn_cvt_pk_fp8_f32(val[2], val[3], p, true);
    *reinterpret_cast<int*>(K + (size_t)row * KROW + j0) = p;
    if (gm) {
        int q = 0;
        q = __builtin_amdgcn_cvt_pk_fp8_f32(gv[0], gv[1], q, false);
        q = __builtin_amdgcn_cvt_pk_fp8_f32(gv[2], gv[3], q, true);
        *reinterpret_cast<int*>(gm + (size_t)row * KROW + j0) = q;
    }
}

// ---- byte transpose K[8192][KROW] -> KT[8224][TROW] via 64x64 LDS tile ----
__global__ __launch_bounds__(256) void transpose_k(const unsigned char* __restrict__ K,
                                                   unsigned char* __restrict__ KT) {
    __shared__ unsigned char tile[64][64];
    int i0 = blockIdx.x * 64;
    int j0 = blockIdx.y * 64;
    int t = threadIdx.x;
    int r = t >> 2, cb = (t & 3) << 4;
    if (j0 + cb < KROW) {
        int4 w = *reinterpret_cast<const int4*>(K + (size_t)(i0 + r) * KROW + j0 + cb);
        *reinterpret_cast<int4*>(&tile[r][cb]) = w;
    }
    __syncthreads();
    int jl = t >> 2, ib = (t & 3) << 4;
    if (j0 + jl < KROW) {
        unsigned char tmp[16];
#pragma unroll
        for (int k = 0; k < 16; ++k) tmp[k] = tile[ib + k][jl];
        *reinterpret_cast<int4*>(KT + (size_t)(j0 + jl) * TROW + i0 + ib) =
            *reinterpret_cast<const int4*>(tmp);
    }
}

__global__ __launch_bounds__(256) void fill_f(float* __restrict__ p, int n, float val) {
    int i = blockIdx.x * 256 + threadIdx.x;
    if (i < n) p[i] = val;
}

// ---- v_pass: v[j] = bval / (KT[j] . u); u in LDS plane-major (conflict-free);
//      2 rows per wave; grid 1028 blocks x 256 thr ----
__global__ __launch_bounds__(256) void v_pass(const unsigned char* __restrict__ KT,
                                              const float* __restrict__ u,
                                              float* __restrict__ v,
                                              int C, float bval) {
    __shared__ float4 wp[4][516];   // quarter q of chunk c at wp[q][c]
    int tx = threadIdx.x;
    {
        const float4* g = reinterpret_cast<const float4*>(u);
        float4 a = g[tx];                // coalesced 16B/lane
        float4 b = g[tx + 256];
        wp[tx & 3][tx >> 2] = a;
        wp[tx & 3][(tx >> 2) + 64] = b;  // (tx+256)>>2 = (tx>>2)+64, same quarter
        float4 c2 = g[tx + 512];
        float4 d2 = g[tx + 768];
        wp[tx & 3][(tx >> 2) + 128] = c2;
        wp[tx & 3][(tx >> 2) + 192] = d2;
        float4 e2 = g[tx + 1024];
        float4 f2 = g[tx + 1280];
        wp[tx & 3][(tx >> 2) + 256] = e2;
        wp[tx & 3][(tx >> 2) + 320] = f2;
        float4 g2 = g[tx + 1536];
        float4 h2 = g[tx + 1792];
        wp[tx & 3][(tx >> 2) + 384] = g2;
        wp[tx & 3][(tx >> 2) + 448] = h2;
    }
    __syncthreads();
    int lane = tx & 63, wv = tx >> 6;
    const int4* KTb = reinterpret_cast<const int4*>(KT);
    int ra = blockIdx.x * 8 + wv * 2;
    const int4* K0 = KTb + (size_t)ra * NTC;
    const int4* K1 = K0 + NTC;
    float p0 = 0.0f, p1 = 0.0f;
#pragma unroll
    for (int s = 0; s < 8; ++s) {
        int ch = s * 64 + lane;
        float4 w0 = wp[0][ch], w1 = wp[1][ch], w2 = wp[2][ch], w3 = wp[3][ch];
        float f[16];
        fp8x16_to_f(K0[ch], f);
        p0 = dotw(f, w0, w1, w2, w3, p0);
        fp8x16_to_f(K1[ch], f);
        p1 = dotw(f, w0, w1, w2, w3, p1);
    }
#pragma unroll
    for (int off = 32; off; off >>= 1) {
        p0 += __shfl_down(p0, off, 64);
        p1 += __shfl_down(p1, off, 64);
    }
    if (lane == 0) {
        v[ra]     = (ra < C)     ? bval / p0 : 0.0f;
        v[ra + 1] = (ra + 1 < C) ? bval / p1 : 0.0f;
    }
}

// ---- u_pass: u[i] = aval / (K[i] . v); v in LDS plane-major; 2 rows per wave;
//      grid 1024 blocks x 256 thr ----
__global__ __launch_bounds__(256) void u_pass(const unsigned char* __restrict__ K,
                                              const float* __restrict__ v,
                                              float* __restrict__ u, float aval) {
    __shared__ float4 wp[4][516];
    int tx = threadIdx.x;
    {
        const float4* g = reinterpret_cast<const float4*>(v);
#pragma unroll
        for (int k = 0; k < 8; ++k) {
            float4 a = g[tx + k * 256];
            wp[tx & 3][(tx >> 2) + k * 64] = a;
        }
        if (tx < 8) {   // float4s 2048..2055 (chunks 512,513)
            float4 a = g[2048 + tx];
            wp[tx & 3][(tx >> 2) + 512] = a;
        }
    }
    __syncthreads();
    int lane = tx & 63, wv = tx >> 6;
    const int4* Kb = reinterpret_cast<const int4*>(K);
    int ra = blockIdx.x * 8 + wv * 2;
    const int4* K0 = Kb + (size_t)ra * NKC;
    const int4* K1 = K0 + NKC;
    float p0 = 0.0f, p1 = 0.0f;
#pragma unroll
    for (int s = 0; s < 8; ++s) {
        int ch = s * 64 + lane;
        float4 w0 = wp[0][ch], w1 = wp[1][ch], w2 = wp[2][ch], w3 = wp[3][ch];
        float f[16];
        fp8x16_to_f(K0[ch], f);
        p0 = dotw(f, w0, w1, w2, w3, p0);
        fp8x16_to_f(K1[ch], f);
        p1 = dotw(f, w0, w1, w2, w3, p1);
    }
    if (lane < 2) {                          // tail chunks 512, 513
        int ch = 512 + lane;
        float4 w0 = wp[0][ch], w1 = wp[1][ch], w2 = wp[2][ch], w3 = wp[3][ch];
        float f[16];
        fp8x16_to_f(K0[ch], f);
        p0 = dotw(f, w0, w1, w2, w3, p0);
        fp8x16_to_f(K1[ch], f);
        p1 = dotw(f, w0, w1, w2, w3, p1);
    }
#pragma unroll
    for (int off = 32; off; off >>= 1) {
        p0 += __shfl_down(p0, off, 64);
        p1 += __shfl_down(p1, off, 64);
    }
    if (lane == 0) {
        u[ra]     = aval / p0;
        u[ra + 1] = aval / p1;
    }
}

// ---- loss reductions ----

__device__ __forceinline__ float2 block_reduce_2(float x, float y, float* sb) {
#pragma unroll
    for (int off = 32; off; off >>= 1) {
        x += __shfl_down(x, off, 64);
        y += __shfl_down(y, off, 64);
    }
    if ((threadIdx.x & 63) == 0) {
        int w = threadIdx.x >> 6;
        sb[w] = x; sb[4 + w] = y;
    }
    __syncthreads();
    float2 r;
    r.x = sb[0] + sb[1] + sb[2] + sb[3];
    r.y = sb[4] + sb[5] + sb[6] + sb[7];
    __syncthreads();
    return r;
}

// GM-path losses: read fp8 K + fp8 GM only (no dist/labels)
__global__ __launch_bounds__(256) void loss1_gm(const unsigned char* __restrict__ K,
                                                const unsigned char* __restrict__ GM,
                                                const float* __restrict__ v,
                                                float* __restrict__ ratio) {
    __shared__ float sb[8];
    int i = blockIdx.x;
    const int4* Kr = reinterpret_cast<const int4*>(K + (size_t)i * KROW);
    const int4* Gr = reinterpret_cast<const int4*>(GM + (size_t)i * KROW);
    const float4* v4 = reinterpret_cast<const float4*>(v);
    float num = 0, den = 0;
    for (int c = threadIdx.x; c < NKC; c += 256) {
        float kf[16], gf[16];
        fp8x16_to_f(Kr[c], kf);
        fp8x16_to_f(Gr[c], gf);
#pragma unroll
        for (int q = 0; q < 4; ++q) {
            float4 w = v4[c * 4 + q];
            float k0 = kf[q * 4 + 0] * w.x, k1 = kf[q * 4 + 1] * w.y;
            float k2 = kf[q * 4 + 2] * w.z, k3 = kf[q * 4 + 3] * w.w;
            den += k0 + k1 + k2 + k3;
            num = fmaf(gf[q * 4 + 0], k0, num);
            num = fmaf(gf[q * 4 + 1], k1, num);
            num = fmaf(gf[q * 4 + 2], k2, num);
            num = fmaf(gf[q * 4 + 3], k3, num);
        }
    }
    float2 r = block_reduce_2(num, den, sb);
    if (threadIdx.x == 0) ratio[i] = r.x / r.y;
}

__global__ __launch_bounds__(256) void loss2_gm(const unsigned char* __restrict__ K,
                                                const unsigned char* __restrict__ GM,
                                                const float* __restrict__ v,
                                                float* __restrict__ ratio) {
    __shared__ float sb[8];
    int i = blockIdx.x;
    const int4* Kr = reinterpret_cast<const int4*>(K + (size_t)i * KROW);
    const int4* Gr = reinterpret_cast<const int4*>(GM + (size_t)i * KROW);
    const float4* v4 = reinterpret_cast<const float4*>(v);
    float num = 0, den = 0;
    for (int c = threadIdx.x; c < NKC; c += 256) {
        float kf[16], gf[16];
        fp8x16_to_f(Kr[c], kf);
        fp8x16_to_f(Gr[c], gf);
        int jb = c * 16;
#pragma unroll
        for (int q = 0; q < 4; ++q) {
            float4 w = v4[c * 4 + q];
            float m0 = (jb + q * 4 + 0 == i) ? 0.0f : 1.0f;
            float m1 = (jb + q * 4 + 1 == i) ? 0.0f : 1.0f;
            float m2 = (jb + q * 4 + 2 == i) ? 0.0f : 1.0f;
            float m3 = (jb + q * 4 + 3 == i) ? 0.0f : 1.0f;
            float k0 = kf[q * 4 + 0] * w.x * m0, k1 = kf[q * 4 + 1] * w.y * m1;
            float k2 = kf[q * 4 + 2] * w.z * m2, k3 = kf[q * 4 + 3] * w.w * m3;
            den += k0 + k1 + k2 + k3;
            num = fmaf(gf[q * 4 + 0], k0, num);
            num = fmaf(gf[q * 4 + 1], k1, num);
            num = fmaf(gf[q * 4 + 2], k2, num);
            num = fmaf(gf[q * 4 + 3], k3, num);
        }
    }
    float2 r = block_reduce_2(num, den, sb);
    if (threadIdx.x == 0) ratio[i] = r.x / r.y;
}

// Fallback losses (R11-proven, no GM buffer)
__global__ __launch_bounds__(256) void loss1_k(const unsigned char* __restrict__ K,
                                               const float* __restrict__ v,
                                               const float* __restrict__ dist,
                                               const int* __restrict__ lab,
                                               float* __restrict__ ratio) {
    __shared__ float sb[8];
    int i = blockIdx.x;
    size_t ib = (size_t)i * C1;
    float d0 = dist[ib];
    const unsigned char* Kr = K + (size_t)i * KROW;
    float num = 0, den = 0;
    for (int j0 = threadIdx.x * 4; j0 < C1; j0 += 1024) {
        int p = *reinterpret_cast<const int*>(Kr + j0);
#pragma unroll
        for (int k = 0; k < 4; ++k) {
            int j = j0 + k;
            int jc = (j < C1) ? j : (C1 - 1);
            float kv = fp8_to_f(p >> (k * 8)) * v[jc];
            float g = gm_label(dist[ib + jc] - d0, lab[ib + jc]);
            den += kv;
            num = fmaf(g, kv, num);
        }
    }
    float2 r = block_reduce_2(num, den, sb);
    if (threadIdx.x == 0) ratio[i] = r.x / r.y;
}

__global__ __launch_bounds__(256) void loss2_k(const unsigned char* __restrict__ K,
                                               const float* __restrict__ v,
                                               const float* __restrict__ dist,
                                               const float* __restrict__ dcol,
                                               float* __restrict__ ratio) {
    __shared__ float sb[8];
    int i = blockIdx.x;
    const unsigned char* Kr = K + (size_t)i * KROW;
    const float* Dr = dist + (size_t)i * C1 + 21;
    float num = 0, den = 0;
    for (int j0 = threadIdx.x * 4; j0 < C2; j0 += 1024) {
        int p = *reinterpret_cast<const int*>(Kr + j0);
#pragma unroll
        for (int k = 0; k < 4; ++k) {
            int j = j0 + k;
            if (j == i) continue;
            float kv = fp8_to_f(p >> (k * 8)) * v[j];
            float h = fmaxf(0.09f + Dr[j] - dcol[j], 0.0f);
            den += kv;
            num = fmaf(h, kv, num);
        }
    }
    float2 r = block_reduce_2(num, den, sb);
    if (threadIdx.x == 0) ratio[i] = r.x / r.y;
}

__global__ __launch_bounds__(256) void final_k(const float* __restrict__ r1,
                                               const float* __restrict__ r2,
                                               float* __restrict__ out) {
    __shared__ float sb[8];
    float s1 = 0, s2 = 0;
    for (int i = threadIdx.x; i < R; i += 256) { s1 += r1[i]; s2 += r2[i]; }
    float2 t = block_reduce_2(s1, s2, sb);
    if (threadIdx.x == 0)
        out[0] = t.x / ((float)R * (float)C1) + t.y / ((float)R * (float)C2);
}

static void run_phase(const unsigned char* K, const unsigned char* KT,
                      float* u, float* v, int C, hipStream_t stream) {
    float aval = 1.0f / (float)R;
    float bval = 1.0f / (float)C;
    fill_f<<<dim3(R / 256), 256, 0, stream>>>(u, R, aval);
    for (int t = 0; t < 50; ++t) {
        v_pass<<<dim3(CPF / 8), 256, 0, stream>>>(KT, u, v, C, bval);
        if (t < 49)
            u_pass<<<dim3(R / 8), 256, 0, stream>>>(K, v, u, aval);
    }
}

extern "C" void kernel_launch(void* const* d_in, const int* in_sizes, int n_in,
                              void* d_out, int out_size, void* d_ws, size_t ws_size,
                              hipStream_t stream) {
    const float* dist = (const float*)d_in[0];
    const int* lab = (const int*)d_in[1];
    float* out = (float*)d_out;
    char* ws = (char*)d_ws;

    const size_t kbytes = (size_t)R * KROW;   // 67,371,008
    const size_t tbytes = (size_t)KROW * TROW;
    size_t small = (size_t)CPF * sizeof(float) + 4 * (size_t)R * sizeof(float);
    size_t need_base = kbytes + tbytes + small;
    size_t need_gm = need_base + kbytes;
    if (ws_size < need_base) return;
    bool useGM = ws_size >= need_gm;

    size_t off = 0;
    unsigned char* K = (unsigned char*)(ws + off);  off += kbytes;
    unsigned char* KT = (unsigned char*)(ws + off); off += tbytes;
    unsigned char* GM = nullptr;
    if (useGM) { GM = (unsigned char*)(ws + off); off += kbytes; }
    float* v = (float*)(ws + off);     off += (size_t)CPF * sizeof(float);
    float* u = (float*)(ws + off);     off += (size_t)R * sizeof(float);
    float* dcol = (float*)(ws + off);  off += (size_t)R * sizeof(float);
    float* rat1 = (float*)(ws + off);  off += (size_t)R * sizeof(float);
    float* rat2 = (float*)(ws + off);  off += (size_t)R * sizeof(float);

    int gb = (KROW / 4 + 255) / 256;   // 9 blocks per row

    // ---- phase 1 ----
    build_k1<<<dim3(gb, R), 256, 0, stream>>>(dist, lab, K, GM);
    transpose_k<<<dim3(R / 64, (KROW + 63) / 64), 256, 0, stream>>>(K, KT);
    run_phase(K, KT, u, v, C1, stream);
    if (useGM)
        loss1_gm<<<dim3(R), 256, 0, stream>>>(K, GM, v, rat1);
    else
        loss1_k<<<dim3(R), 256, 0, stream>>>(K, v, dist, lab, rat1);

    // ---- phase 2 (reuses K and KT buffers) ----
    diag_k<<<dim3(R / 256), 256, 0, stream>>>(dist, dcol);
    build_k2<<<dim3(gb, R), 256, 0, stream>>>(dist, dcol, K, GM);
    transpose_k<<<dim3(R / 64, (KROW + 63) / 64), 256, 0, stream>>>(K, KT);
    run_phase(K, KT, u, v, C2, stream);
    if (useGM)
        loss2_gm<<<dim3(R), 256, 0, stream>>>(K, GM, v, rat2);
    else
        loss2_k<<<dim3(R), 256, 0, stream>>>(K, v, dist, dcol, rat2);

    final_k<<<dim3(1), 256, 0, stream>>>(rat1, rat2, out);
}

// Round 14
// 2952.980 us; speedup vs baseline: 6.5724x; 1.1416x over previous
//
#include <hip/hip_runtime.h>

#define R     8192
#define C1    8213
#define C2    8192
#define KROW  8224      // K/GM row stride in BYTES (514 x 16B chunks, zero-padded)
#define TROW  8192      // KT row stride in BYTES (512 x 16B chunks)
#define NKC   514
#define NTC   512
#define CPF   8224      // v length in floats
#define BLKJ  1024      // outputs per build block

typedef float f32x2 __attribute__((ext_vector_type(2)));

__device__ __forceinline__ void fp8x16_to_f(const int4 w, float f[16]) {
    f32x2 p;
    p = __builtin_amdgcn_cvt_pk_f32_fp8(w.x, false); f[0]  = p.x; f[1]  = p.y;
    p = __builtin_amdgcn_cvt_pk_f32_fp8(w.x, true);  f[2]  = p.x; f[3]  = p.y;
    p = __builtin_amdgcn_cvt_pk_f32_fp8(w.y, false); f[4]  = p.x; f[5]  = p.y;
    p = __builtin_amdgcn_cvt_pk_f32_fp8(w.y, true);  f[6]  = p.x; f[7]  = p.y;
    p = __builtin_amdgcn_cvt_pk_f32_fp8(w.z, false); f[8]  = p.x; f[9]  = p.y;
    p = __builtin_amdgcn_cvt_pk_f32_fp8(w.z, true);  f[10] = p.x; f[11] = p.y;
    p = __builtin_amdgcn_cvt_pk_f32_fp8(w.w, false); f[12] = p.x; f[13] = p.y;
    p = __builtin_amdgcn_cvt_pk_f32_fp8(w.w, true);  f[14] = p.x; f[15] = p.y;
}

__device__ __forceinline__ float fp8_to_f(int byte) {
    f32x2 p = __builtin_amdgcn_cvt_pk_f32_fp8(byte & 0xff, false);
    return p.x;
}

__device__ __forceinline__ float gm_label(float sc, int lab) {
    if (lab == 0) return fmaxf(-0.02f - sc, 0.0f) + fmaxf(sc, 0.0f);
    if (lab == 3) return fmaxf(0.09f + sc, 0.0f);
    return fmaxf(0.05f + sc, 0.0f) + fmaxf(-0.09f - sc, 0.0f); // labels 1|2
}

__device__ __forceinline__ float kval(float gm) {
    // K = exp(-M/REG), M = exp(-GM), REG = -0.2 -> exp(5*exp(-GM)); hw exp
    return __expf(5.0f * __expf(-gm));
}

__device__ __forceinline__ float dotw(const float f[16], float4 w0, float4 w1,
                                      float4 w2, float4 w3, float p) {
    p = fmaf(f[0], w0.x, p);  p = fmaf(f[1], w0.y, p);
    p = fmaf(f[2], w0.z, p);  p = fmaf(f[3], w0.w, p);
    p = fmaf(f[4], w1.x, p);  p = fmaf(f[5], w1.y, p);
    p = fmaf(f[6], w1.z, p);  p = fmaf(f[7], w1.w, p);
    p = fmaf(f[8], w2.x, p);  p = fmaf(f[9], w2.y, p);
    p = fmaf(f[10], w2.z, p); p = fmaf(f[11], w2.w, p);
    p = fmaf(f[12], w3.x, p); p = fmaf(f[13], w3.y, p);
    p = fmaf(f[14], w3.z, p); p = fmaf(f[15], w3.w, p);
    return p;
}

// ---- alignment-fixed build kernels: stage row window via aligned float4/int4 ----

__global__ __launch_bounds__(256) void build_k1a(const float* __restrict__ dist,
                                                 const int* __restrict__ lab,
                                                 unsigned char* __restrict__ K,
                                                 unsigned char* __restrict__ gm) {
    __shared__ float ds[BLKJ + 4];
    __shared__ int dl[BLKJ + 4];
    int row = blockIdx.y;
    int c0 = blockIdx.x * BLKJ;
    int tx = threadIdx.x;
    size_t ib = (size_t)row * C1;
    int sh = row & 3;                          // ib mod 4
    long base4 = ((long)ib + c0 - sh) >> 2;    // aligned float4 index
    const long tot4 = ((long)R * C1) >> 2;
    {
        const float4* g4 = reinterpret_cast<const float4*>(dist);
        const int4* l4 = reinterpret_cast<const int4*>(lab);
        long i4 = base4 + tx;
        float4 dv = make_float4(0, 0, 0, 0);
        int4 lv = make_int4(0, 0, 0, 0);
        if (i4 >= 0 && i4 < tot4) { dv = g4[i4]; lv = l4[i4]; }
        *reinterpret_cast<float4*>(&ds[tx * 4]) = dv;
        *reinterpret_cast<int4*>(&dl[tx * 4]) = lv;
        if (tx == 0) {
            long j4 = base4 + 256;
            float4 dv2 = make_float4(0, 0, 0, 0);
            int4 lv2 = make_int4(0, 0, 0, 0);
            if (j4 >= 0 && j4 < tot4) { dv2 = g4[j4]; lv2 = l4[j4]; }
            *reinterpret_cast<float4*>(&ds[1024]) = dv2;
            *reinterpret_cast<int4*>(&dl[1024]) = lv2;
        }
    }
    __syncthreads();
    int j0 = c0 + tx * 4;
    if (j0 >= KROW) return;
    float d0 = dist[ib];
    float val[4], gv[4];
#pragma unroll
    for (int k = 0; k < 4; ++k) {
        int j = j0 + k;
        val[k] = 0.0f; gv[k] = 0.0f;
        if (j < C1) {
            int li = tx * 4 + sh + k;
            float g = gm_label(ds[li] - d0, dl[li]);
            gv[k] = g;
            val[k] = kval(g);
        }
    }
    int p = 0;
    p = __builtin_amdgcn_cvt_pk_fp8_f32(val[0], val[1], p, false);
    p = __builtin_amdgcn_cvt_pk_fp8_f32(val[2], val[3], p, true);
    *reinterpret_cast<int*>(K + (size_t)row * KROW + j0) = p;
    if (gm) {
        int q = 0;
        q = __builtin_amdgcn_cvt_pk_fp8_f32(gv[0], gv[1], q, false);
        q = __builtin_amdgcn_cvt_pk_fp8_f32(gv[2], gv[3], q, true);
        *reinterpret_cast<int*>(gm + (size_t)row * KROW + j0) = q;
    }
}

__global__ __launch_bounds__(256) void diag_k(const float* __restrict__ dist,
                                              float* __restrict__ dcol) {
    int j = blockIdx.x * 256 + threadIdx.x;
    if (j < R) dcol[j] = dist[(size_t)j * C1 + 21 + j];
}

__global__ __launch_bounds__(256) void build_k2a(const float* __restrict__ dist,
                                                 const float* __restrict__ dcol,
                                                 unsigned char* __restrict__ K,
                                                 unsigned char* __restrict__ gm) {
    __shared__ float ds[BLKJ + 4];
    int row = blockIdx.y;
    int c0 = blockIdx.x * BLKJ;
    int tx = threadIdx.x;
    size_t ib = (size_t)row * C1 + 21;
    int sh = (int)(ib & 3);
    long base4 = ((long)ib + c0 - sh) >> 2;
    const long tot4 = ((long)R * C1) >> 2;
    {
        const float4* g4 = reinterpret_cast<const float4*>(dist);
        long i4 = base4 + tx;
        float4 dv = make_float4(0, 0, 0, 0);
        if (i4 >= 0 && i4 < tot4) dv = g4[i4];
        *reinterpret_cast<float4*>(&ds[tx * 4]) = dv;
        if (tx == 0) {
            long j4 = base4 + 256;
            float4 dv2 = make_float4(0, 0, 0, 0);
            if (j4 >= 0 && j4 < tot4) dv2 = g4[j4];
            *reinterpret_cast<float4*>(&ds[1024]) = dv2;
        }
    }
    __syncthreads();
    int j0 = c0 + tx * 4;
    if (j0 >= KROW) return;
    float val[4], gv[4];
#pragma unroll
    for (int k = 0; k < 4; ++k) {
        int j = j0 + k;
        val[k] = 0.0f; gv[k] = 0.0f;
        if (j < C2) {
            float s = ds[tx * 4 + sh + k] - dcol[j];
            float g = (j == row) ? 0.0f : fmaxf(0.09f + s, 0.0f);
            gv[k] = g;
            val[k] = kval(g);
        }
    }
    int p = 0;
    p = __builtin_amdgcn_cvt_pk_fp8_f32(val[0], val[1], p, false);
    p = __builtin_amdgcn_cvt_pk_fp8_f32(val[2], val[3], p, true);
    *reinterpret_cast<int*>(K + (size_t)row * KROW + j0) = p;
    if (gm) {
        int q = 0;
        q = __builtin_amdgcn_cvt_pk_fp8_f32(gv[0], gv[1], q, false);
        q = __builtin_amdgcn_cvt_pk_fp8_f32(gv[2], gv[3], q, true);
        *reinterpret_cast<int*>(gm + (size_t)row * KROW + j0) = q;
    }
}

// ---- byte transpose K[8192][KROW] -> KT[8224][TROW] via 64x64 LDS tile ----
__global__ __launch_bounds__(256) void transpose_k(const unsigned char* __restrict__ K,
                                                   unsigned char* __restrict__ KT) {
    __shared__ unsigned char tile[64][64];
    int i0 = blockIdx.x * 64;
    int j0 = blockIdx.y * 64;
    int t = threadIdx.x;
    int r = t >> 2, cb = (t & 3) << 4;
    if (j0 + cb < KROW) {
        int4 w = *reinterpret_cast<const int4*>(K + (size_t)(i0 + r) * KROW + j0 + cb);
        *reinterpret_cast<int4*>(&tile[r][cb]) = w;
    }
    __syncthreads();
    int jl = t >> 2, ib = (t & 3) << 4;
    if (j0 + jl < KROW) {
        unsigned char tmp[16];
#pragma unroll
        for (int k = 0; k < 16; ++k) tmp[k] = tile[ib + k][jl];
        *reinterpret_cast<int4*>(KT + (size_t)(j0 + jl) * TROW + i0 + ib) =
            *reinterpret_cast<const int4*>(tmp);
    }
}

__global__ __launch_bounds__(256) void fill_f(float* __restrict__ p, int n, float val) {
    int i = blockIdx.x * 256 + threadIdx.x;
    if (i < n) p[i] = val;
}

// ---- shared pass body (plane-major LDS staging, R13-proven) ----

__device__ __forceinline__ void vpass_body(const unsigned char* __restrict__ KT,
                                           const float* __restrict__ u,
                                           float* __restrict__ v,
                                           int bb, int C, float bval,
                                           float4 (*wp)[516]) {
    int tx = threadIdx.x;
    {
        const float4* g = reinterpret_cast<const float4*>(u);
#pragma unroll
        for (int k = 0; k < 8; ++k) {
            float4 a = g[tx + k * 256];
            wp[tx & 3][(tx >> 2) + k * 64] = a;
        }
    }
    __syncthreads();
    int lane = tx & 63, wv = tx >> 6;
    const int4* KTb = reinterpret_cast<const int4*>(KT);
    int ra = bb * 8 + wv * 2;
    const int4* K0 = KTb + (size_t)ra * NTC;
    const int4* K1 = K0 + NTC;
    float p0 = 0.0f, p1 = 0.0f;
#pragma unroll
    for (int s = 0; s < 8; ++s) {
        int ch = s * 64 + lane;
        float4 w0 = wp[0][ch], w1 = wp[1][ch], w2 = wp[2][ch], w3 = wp[3][ch];
        float f[16];
        fp8x16_to_f(K0[ch], f);
        p0 = dotw(f, w0, w1, w2, w3, p0);
        fp8x16_to_f(K1[ch], f);
        p1 = dotw(f, w0, w1, w2, w3, p1);
    }
#pragma unroll
    for (int off = 32; off; off >>= 1) {
        p0 += __shfl_down(p0, off, 64);
        p1 += __shfl_down(p1, off, 64);
    }
    if (lane == 0) {
        v[ra]     = (ra < C)     ? bval / p0 : 0.0f;
        v[ra + 1] = (ra + 1 < C) ? bval / p1 : 0.0f;
    }
}

__device__ __forceinline__ void upass_body(const unsigned char* __restrict__ K,
                                           const float* __restrict__ v,
                                           float* __restrict__ u,
                                           int bb, float aval,
                                           float4 (*wp)[516]) {
    int tx = threadIdx.x;
    {
        const float4* g = reinterpret_cast<const float4*>(v);
#pragma unroll
        for (int k = 0; k < 8; ++k) {
            float4 a = g[tx + k * 256];
            wp[tx & 3][(tx >> 2) + k * 64] = a;
        }
        if (tx < 8) {
            float4 a = g[2048 + tx];
            wp[tx & 3][(tx >> 2) + 512] = a;
        }
    }
    __syncthreads();
    int lane = tx & 63, wv = tx >> 6;
    const int4* Kb = reinterpret_cast<const int4*>(K);
    int ra = bb * 8 + wv * 2;
    const int4* K0 = Kb + (size_t)ra * NKC;
    const int4* K1 = K0 + NKC;
    float p0 = 0.0f, p1 = 0.0f;
#pragma unroll
    for (int s = 0; s < 8; ++s) {
        int ch = s * 64 + lane;
        float4 w0 = wp[0][ch], w1 = wp[1][ch], w2 = wp[2][ch], w3 = wp[3][ch];
        float f[16];
        fp8x16_to_f(K0[ch], f);
        p0 = dotw(f, w0, w1, w2, w3, p0);
        fp8x16_to_f(K1[ch], f);
        p1 = dotw(f, w0, w1, w2, w3, p1);
    }
    if (lane < 2) {
        int ch = 512 + lane;
        float4 w0 = wp[0][ch], w1 = wp[1][ch], w2 = wp[2][ch], w3 = wp[3][ch];
        float f[16];
        fp8x16_to_f(K0[ch], f);
        p0 = dotw(f, w0, w1, w2, w3, p0);
        fp8x16_to_f(K1[ch], f);
        p1 = dotw(f, w0, w1, w2, w3, p1);
    }
#pragma unroll
    for (int off = 32; off; off >>= 1) {
        p0 += __shfl_down(p0, off, 64);
        p1 += __shfl_down(p1, off, 64);
    }
    if (lane == 0) {
        u[ra]     = aval / p0;
        u[ra + 1] = aval / p1;
    }
}

// single-phase passes (sequential fallback)
__global__ __launch_bounds__(256) void v_pass(const unsigned char* __restrict__ KT,
                                              const float* __restrict__ u,
                                              float* __restrict__ v, int C, float bval) {
    __shared__ float4 wp[4][516];
    vpass_body(KT, u, v, blockIdx.x, C, bval, wp);
}

__global__ __launch_bounds__(256) void u_pass(const unsigned char* __restrict__ K,
                                              const float* __restrict__ v,
                                              float* __restrict__ u, float aval) {
    __shared__ float4 wp[4][516];
    upass_body(K, v, u, blockIdx.x, aval, wp);
}

// dual-phase passes: first half of grid = phase 1, second half = phase 2
__global__ __launch_bounds__(256) void v_pass_dual(const unsigned char* __restrict__ KT1,
                                                   const unsigned char* __restrict__ KT2,
                                                   const float* __restrict__ u,   // u1 | u2
                                                   float* __restrict__ v,         // v1 | v2
                                                   float bval1, float bval2) {
    __shared__ float4 wp[4][516];
    int b = blockIdx.x;
    if (b < 1028)
        vpass_body(KT1, u, v, b, C1, bval1, wp);
    else
        vpass_body(KT2, u + R, v + CPF, b - 1028, C2, bval2, wp);
}

__global__ __launch_bounds__(256) void u_pass_dual(const unsigned char* __restrict__ K1,
                                                   const unsigned char* __restrict__ K2,
                                                   const float* __restrict__ v,
                                                   float* __restrict__ u, float aval) {
    __shared__ float4 wp[4][516];
    int b = blockIdx.x;
    if (b < 1024)
        upass_body(K1, v, u, b, aval, wp);
    else
        upass_body(K2, v + CPF, u + R, b - 1024, aval, wp);
}

// ---- loss reductions ----

__device__ __forceinline__ float2 block_reduce_2(float x, float y, float* sb) {
#pragma unroll
    for (int off = 32; off; off >>= 1) {
        x += __shfl_down(x, off, 64);
        y += __shfl_down(y, off, 64);
    }
    if ((threadIdx.x & 63) == 0) {
        int w = threadIdx.x >> 6;
        sb[w] = x; sb[4 + w] = y;
    }
    __syncthreads();
    float2 r;
    r.x = sb[0] + sb[1] + sb[2] + sb[3];
    r.y = sb[4] + sb[5] + sb[6] + sb[7];
    __syncthreads();
    return r;
}

__global__ __launch_bounds__(256) void loss1_gm(const unsigned char* __restrict__ K,
                                                const unsigned char* __restrict__ GM,
                                                const float* __restrict__ v,
                                                float* __restrict__ ratio) {
    __shared__ float sb[8];
    int i = blockIdx.x;
    const int4* Kr = reinterpret_cast<const int4*>(K + (size_t)i * KROW);
    const int4* Gr = reinterpret_cast<const int4*>(GM + (size_t)i * KROW);
    const float4* v4 = reinterpret_cast<const float4*>(v);
    float num = 0, den = 0;
    for (int c = threadIdx.x; c < NKC; c += 256) {
        float kf[16], gf[16];
        fp8x16_to_f(Kr[c], kf);
        fp8x16_to_f(Gr[c], gf);
#pragma unroll
        for (int q = 0; q < 4; ++q) {
            float4 w = v4[c * 4 + q];
            float k0 = kf[q * 4 + 0] * w.x, k1 = kf[q * 4 + 1] * w.y;
            float k2 = kf[q * 4 + 2] * w.z, k3 = kf[q * 4 + 3] * w.w;
            den += k0 + k1 + k2 + k3;
            num = fmaf(gf[q * 4 + 0], k0, num);
            num = fmaf(gf[q * 4 + 1], k1, num);
            num = fmaf(gf[q * 4 + 2], k2, num);
            num = fmaf(gf[q * 4 + 3], k3, num);
        }
    }
    float2 r = block_reduce_2(num, den, sb);
    if (threadIdx.x == 0) ratio[i] = r.x / r.y;
}

__global__ __launch_bounds__(256) void loss2_gm(const unsigned char* __restrict__ K,
                                                const unsigned char* __restrict__ GM,
                                                const float* __restrict__ v,
                                                float* __restrict__ ratio) {
    __shared__ float sb[8];
    int i = blockIdx.x;
    const int4* Kr = reinterpret_cast<const int4*>(K + (size_t)i * KROW);
    const int4* Gr = reinterpret_cast<const int4*>(GM + (size_t)i * KROW);
    const float4* v4 = reinterpret_cast<const float4*>(v);
    float num = 0, den = 0;
    for (int c = threadIdx.x; c < NKC; c += 256) {
        float kf[16], gf[16];
        fp8x16_to_f(Kr[c], kf);
        fp8x16_to_f(Gr[c], gf);
        int jb = c * 16;
#pragma unroll
        for (int q = 0; q < 4; ++q) {
            float4 w = v4[c * 4 + q];
            float m0 = (jb + q * 4 + 0 == i) ? 0.0f : 1.0f;
            float m1 = (jb + q * 4 + 1 == i) ? 0.0f : 1.0f;
            float m2 = (jb + q * 4 + 2 == i) ? 0.0f : 1.0f;
            float m3 = (jb + q * 4 + 3 == i) ? 0.0f : 1.0f;
            float k0 = kf[q * 4 + 0] * w.x * m0, k1 = kf[q * 4 + 1] * w.y * m1;
            float k2 = kf[q * 4 + 2] * w.z * m2, k3 = kf[q * 4 + 3] * w.w * m3;
            den += k0 + k1 + k2 + k3;
            num = fmaf(gf[q * 4 + 0], k0, num);
            num = fmaf(gf[q * 4 + 1], k1, num);
            num = fmaf(gf[q * 4 + 2], k2, num);
            num = fmaf(gf[q * 4 + 3], k3, num);
        }
    }
    float2 r = block_reduce_2(num, den, sb);
    if (threadIdx.x == 0) ratio[i] = r.x / r.y;
}

// fallback losses (read dist directly)
__global__ __launch_bounds__(256) void loss1_k(const unsigned char* __restrict__ K,
                                               const float* __restrict__ v,
                                               const float* __restrict__ dist,
                                               const int* __restrict__ lab,
                                               float* __restrict__ ratio) {
    __shared__ float sb[8];
    int i = blockIdx.x;
    size_t ib = (size_t)i * C1;
    float d0 = dist[ib];
    const unsigned char* Kr = K + (size_t)i * KROW;
    float num = 0, den = 0;
    for (int j0 = threadIdx.x * 4; j0 < C1; j0 += 1024) {
        int p = *reinterpret_cast<const int*>(Kr + j0);
#pragma unroll
        for (int k = 0; k < 4; ++k) {
            int j = j0 + k;
            int jc = (j < C1) ? j : (C1 - 1);
            float kv = fp8_to_f(p >> (k * 8)) * v[jc];
            float g = gm_label(dist[ib + jc] - d0, lab[ib + jc]);
            den += kv;
            num = fmaf(g, kv, num);
        }
    }
    float2 r = block_reduce_2(num, den, sb);
    if (threadIdx.x == 0) ratio[i] = r.x / r.y;
}

__global__ __launch_bounds__(256) void loss2_k(const unsigned char* __restrict__ K,
                                               const float* __restrict__ v,
                                               const float* __restrict__ dist,
                                               const float* __restrict__ dcol,
                                               float* __restrict__ ratio) {
    __shared__ float sb[8];
    int i = blockIdx.x;
    const unsigned char* Kr = K + (size_t)i * KROW;
    const float* Dr = dist + (size_t)i * C1 + 21;
    float num = 0, den = 0;
    for (int j0 = threadIdx.x * 4; j0 < C2; j0 += 1024) {
        int p = *reinterpret_cast<const int*>(Kr + j0);
#pragma unroll
        for (int k = 0; k < 4; ++k) {
            int j = j0 + k;
            if (j == i) continue;
            float kv = fp8_to_f(p >> (k * 8)) * v[j];
            float h = fmaxf(0.09f + Dr[j] - dcol[j], 0.0f);
            den += kv;
            num = fmaf(h, kv, num);
        }
    }
    float2 r = block_reduce_2(num, den, sb);
    if (threadIdx.x == 0) ratio[i] = r.x / r.y;
}

__global__ __launch_bounds__(256) void final_k(const float* __restrict__ r1,
                                               const float* __restrict__ r2,
                                               float* __restrict__ out) {
    __shared__ float sb[8];
    float s1 = 0, s2 = 0;
    for (int i = threadIdx.x; i < R; i += 256) { s1 += r1[i]; s2 += r2[i]; }
    float2 t = block_reduce_2(s1, s2, sb);
    if (threadIdx.x == 0)
        out[0] = t.x / ((float)R * (float)C1) + t.y / ((float)R * (float)C2);
}

static void run_phase_seq(const unsigned char* K, const unsigned char* KT,
                          float* u, float* v, int C, hipStream_t stream) {
    float aval = 1.0f / (float)R;
    float bval = 1.0f / (float)C;
    fill_f<<<dim3(R / 256), 256, 0, stream>>>(u, R, aval);
    for (int t = 0; t < 50; ++t) {
        v_pass<<<dim3(CPF / 8), 256, 0, stream>>>(KT, u, v, C, bval);
        if (t < 49)
            u_pass<<<dim3(R / 8), 256, 0, stream>>>(K, v, u, aval);
    }
}

extern "C" void kernel_launch(void* const* d_in, const int* in_sizes, int n_in,
                              void* d_out, int out_size, void* d_ws, size_t ws_size,
                              hipStream_t stream) {
    const float* dist = (const float*)d_in[0];
    const int* lab = (const int*)d_in[1];
    float* out = (float*)d_out;
    char* ws = (char*)d_ws;

    const size_t kb = (size_t)R * KROW;       // 67,371,008 (== KROW*TROW)
    const size_t small_dual = (2 * (size_t)CPF + 2 * R + 3 * R) * sizeof(float);
    const size_t small_seq = ((size_t)CPF + 4 * R) * sizeof(float);
    const size_t need_dual = 6 * kb + small_dual;     // ~404 MB
    const size_t need_gm_seq = 3 * kb + small_seq;    // ~202 MB
    const size_t need_base = 2 * kb + small_seq;      // ~135 MB
    if (ws_size < need_base) return;

    const float aval = 1.0f / (float)R;
    const int gbx = (KROW + BLKJ - 1) / BLKJ;         // 9
    const dim3 gT(R / 64, (KROW + 63) / 64);

    if (ws_size >= need_dual) {
        // ---- dual-phase path ----
        size_t off = 0;
        unsigned char* K1 = (unsigned char*)(ws + off);  off += kb;
        unsigned char* K2 = (unsigned char*)(ws + off);  off += kb;
        unsigned char* K1T = (unsigned char*)(ws + off); off += kb;
        unsigned char* K2T = (unsigned char*)(ws + off); off += kb;
        unsigned char* GM1 = (unsigned char*)(ws + off); off += kb;
        unsigned char* GM2 = (unsigned char*)(ws + off); off += kb;
        float* v = (float*)(ws + off);    off += 2 * (size_t)CPF * sizeof(float);
        float* u = (float*)(ws + off);    off += 2 * (size_t)R * sizeof(float);
        float* dcol = (float*)(ws + off); off += (size_t)R * sizeof(float);
        float* rat1 = (float*)(ws + off); off += (size_t)R * sizeof(float);
        float* rat2 = (float*)(ws + off); off += (size_t)R * sizeof(float);

        diag_k<<<dim3(R / 256), 256, 0, stream>>>(dist, dcol);
        build_k1a<<<dim3(gbx, R), 256, 0, stream>>>(dist, lab, K1, GM1);
        build_k2a<<<dim3(gbx, R), 256, 0, stream>>>(dist, dcol, K2, GM2);
        transpose_k<<<gT, 256, 0, stream>>>(K1, K1T);
        transpose_k<<<gT, 256, 0, stream>>>(K2, K2T);
        fill_f<<<dim3(2 * R / 256), 256, 0, stream>>>(u, 2 * R, aval);
        for (int t = 0; t < 50; ++t) {
            v_pass_dual<<<dim3(2 * (CPF / 8)), 256, 0, stream>>>(
                K1T, K2T, u, v, 1.0f / (float)C1, 1.0f / (float)C2);
            if (t < 49)
                u_pass_dual<<<dim3(2 * (R / 8)), 256, 0, stream>>>(K1, K2, v, u, aval);
        }
        loss1_gm<<<dim3(R), 256, 0, stream>>>(K1, GM1, v, rat1);
        loss2_gm<<<dim3(R), 256, 0, stream>>>(K2, GM2, v + CPF, rat2);
        final_k<<<dim3(1), 256, 0, stream>>>(rat1, rat2, out);
        return;
    }

    // ---- sequential path (R13 structure, aligned builds) ----
    bool useGM = ws_size >= need_gm_seq;
    size_t off = 0;
    unsigned char* K = (unsigned char*)(ws + off);  off += kb;
    unsigned char* KT = (unsigned char*)(ws + off); off += kb;
    unsigned char* GM = nullptr;
    if (useGM) { GM = (unsigned char*)(ws + off); off += kb; }
    float* v = (float*)(ws + off);    off += (size_t)CPF * sizeof(float);
    float* u = (float*)(ws + off);    off += (size_t)R * sizeof(float);
    float* dcol = (float*)(ws + off); off += (size_t)R * sizeof(float);
    float* rat1 = (float*)(ws + off); off += (size_t)R * sizeof(float);
    float* rat2 = (float*)(ws + off); off += (size_t)R * sizeof(float);

    build_k1a<<<dim3(gbx, R), 256, 0, stream>>>(dist, lab, K, GM);
    transpose_k<<<gT, 256, 0, stream>>>(K, KT);
    run_phase_seq(K, KT, u, v, C1, stream);
    if (useGM)
        loss1_gm<<<dim3(R), 256, 0, stream>>>(K, GM, v, rat1);
    else
        loss1_k<<<dim3(R), 256, 0, stream>>>(K, v, dist, lab, rat1);

    diag_k<<<dim3(R / 256), 256, 0, stream>>>(dist, dcol);
    build_k2a<<<dim3(gbx, R), 256, 0, stream>>>(dist, dcol, K, GM);
    transpose_k<<<gT, 256, 0, stream>>>(K, KT);
    run_phase_seq(K, KT, u, v, C2, stream);
    if (useGM)
        loss2_gm<<<dim3(R), 256, 0, stream>>>(K, GM, v, rat2);
    else
        loss2_k<<<dim3(R), 256, 0, stream>>>(K, v, dist, dcol, rat2);

    final_k<<<dim3(1), 256, 0, stream>>>(rat1, rat2, out);
}